// Round 3
// baseline (229.802 us; speedup 1.0000x reference)
//
#include <hip/hip_runtime.h>
#include <math.h>

constexpr int CBS   = 8;
constexpr int CN    = 1024;
constexpr int CFIN  = 256;
constexpr int CNH   = 8;
constexpr int CFOUT = 64;

using f32x4 = __attribute__((ext_vector_type(4))) float;
using s16x8 = __attribute__((ext_vector_type(8))) short;

__device__ __forceinline__ short f2bf(float x) {
  __bf16 b = (__bf16)x;
  return __builtin_bit_cast(short, b);
}
__device__ __forceinline__ float bf2f(short s) {
  __bf16 b = __builtin_bit_cast(__bf16, s);
  return (float)b;
}

// ---------------------------------------------------------------------------
// Kernel 1: hp = h@w (f32 VALU GEMM), fused epilogue:
//   - vsrc/vdst (tanh dot a_src/a_dst, wave shuffle reduce)
//   - LDS transpose + hi/lo bf16 split -> hiT/loT [bh][o][n]  (no hp f32!)
// Block: 256 thr = 4 waves; 64 n-rows x 64 o per block; K tiled 2x128.
// LDS: w_s 32KB + h_s 32KB -> 2 blocks/CU. s_t aliases w_s for transpose.
// ---------------------------------------------------------------------------
__global__ __launch_bounds__(256) void gat_hprime_fused(
    const float* __restrict__ h, const float* __restrict__ w,
    const float* __restrict__ a_src, const float* __restrict__ a_dst,
    short* __restrict__ hiT, short* __restrict__ loT,
    float* __restrict__ vsrc, float* __restrict__ vdst) {
  __shared__ float w_s[128 * 64];     // [kk][o] chunk
  __shared__ float h_s[64 * 128];     // [row][kk] chunk
  float* s_t = w_s;                   // 64*65 f32 transpose buffer (aliased)

  const int t    = threadIdx.x;
  const int blk  = blockIdx.x;        // bh*16 + nt
  const int nt   = blk & 15;
  const int bh   = blk >> 4;
  const int head = bh & 7;
  const int b    = bh >> 3;
  const int n0   = nt * 64;
  const int o    = t & 63, wid = t >> 6;

  const float* wg0 = w + (size_t)head * CFIN * CFOUT;
  const float* hg  = h + ((size_t)b * CN + n0) * CFIN;

  float acc[16];
  #pragma unroll
  for (int q = 0; q < 16; ++q) acc[q] = 0.f;

  for (int k0 = 0; k0 < CFIN; k0 += 128) {
    // stage w chunk: 128x64 f32 contiguous
    const float* wg = wg0 + (size_t)k0 * CFOUT;
    #pragma unroll
    for (int i = 0; i < 8; ++i) {
      int idx = (i * 256 + t) * 4;
      *(float4*)(w_s + idx) = *(const float4*)(wg + idx);
    }
    // stage h chunk: 64 rows x 128 k
    #pragma unroll
    for (int i = 0; i < 8; ++i) {
      int fidx = i * 256 + t;
      int row = fidx >> 5, col = (fidx & 31) * 4;
      *(float4*)(h_s + row * 128 + col) = *(const float4*)(hg + (size_t)row * CFIN + k0 + col);
    }
    __syncthreads();

    for (int kk = 0; kk < 128; kk += 4) {
      float w0 = w_s[(kk + 0) * 64 + o];
      float w1 = w_s[(kk + 1) * 64 + o];
      float w2 = w_s[(kk + 2) * 64 + o];
      float w3 = w_s[(kk + 3) * 64 + o];
      #pragma unroll
      for (int q = 0; q < 16; ++q) {
        float4 hv = *(const float4*)(h_s + (wid * 16 + q) * 128 + kk);
        acc[q] = fmaf(hv.x, w0, acc[q]);
        acc[q] = fmaf(hv.y, w1, acc[q]);
        acc[q] = fmaf(hv.z, w2, acc[q]);
        acc[q] = fmaf(hv.w, w3, acc[q]);
      }
    }
    __syncthreads();   // protects restage AND s_t aliasing after last chunk
  }

  // vsrc / vdst
  const float asv = a_src[head * CFOUT + o];
  const float adv = a_dst[head * CFOUT + o];
  #pragma unroll
  for (int q = 0; q < 16; ++q) {
    float tv = tanhf(acc[q]);
    float vs = tv * asv, vd = tv * adv;
    for (int mm = 32; mm; mm >>= 1) {
      vs += __shfl_xor(vs, mm, 64);
      vd += __shfl_xor(vd, mm, 64);
    }
    if (o == 0) {
      int n = n0 + wid * 16 + q;
      vsrc[(size_t)bh * CN + n] = vs;
      vdst[(size_t)bh * CN + n] = vd;
    }
  }

  // transpose via LDS, split hi/lo bf16, write [bh][o][n]
  #pragma unroll
  for (int q = 0; q < 16; ++q) s_t[(wid * 16 + q) * 65 + o] = acc[q];
  __syncthreads();

  {
    const int o2 = t >> 2, nc = (t & 3) * 16;
    unsigned int hw[8], lw[8];
    #pragma unroll
    for (int i = 0; i < 16; i += 2) {
      float v0 = s_t[(nc + i) * 65 + o2];
      float v1 = s_t[(nc + i + 1) * 65 + o2];
      short h0 = f2bf(v0), h1 = f2bf(v1);
      short l0 = f2bf(v0 - bf2f(h0)), l1 = f2bf(v1 - bf2f(h1));
      hw[i >> 1] = (unsigned int)(unsigned short)h0 | ((unsigned int)(unsigned short)h1 << 16);
      lw[i >> 1] = (unsigned int)(unsigned short)l0 | ((unsigned int)(unsigned short)l1 << 16);
    }
    size_t base = (((size_t)bh * CFOUT + o2) * CN + n0 + nc) >> 1;  // uint index
    uint4* hp4 = (uint4*)((unsigned int*)hiT + base);
    uint4* lp4 = (uint4*)((unsigned int*)loT + base);
    hp4[0] = make_uint4(hw[0], hw[1], hw[2], hw[3]);
    hp4[1] = make_uint4(hw[4], hw[5], hw[6], hw[7]);
    lp4[0] = make_uint4(lw[0], lw[1], lw[2], lw[3]);
    lp4[1] = make_uint4(lw[4], lw[5], lw[6], lw[7]);
  }
}

// ---------------------------------------------------------------------------
// Kernel 2: pack adj (int32 0/1) into bitmask, 1 bit per (b,i,j)
// ---------------------------------------------------------------------------
__global__ __launch_bounds__(256) void pack_adj(
    const int* __restrict__ adj, unsigned long long* __restrict__ mask) {
  const int t = threadIdx.x, lane = t & 63, w = t >> 6;
  const long long wid = (long long)blockIdx.x * 4 + w;   // (b*1024+i)*16 + jw
  const int jw = (int)(wid & 15);
  const long long bi = wid >> 4;
  int a = adj[bi * 1024 + jw * 64 + lane];
  unsigned long long m = __ballot(a > 0);
  if (lane == 0) mask[wid] = m;
}

// ---------------------------------------------------------------------------
// Kernel 3: masked-exp GEMM via MFMA. 16 rows/wave, 64 rows/block, grid 1024.
//   A[m][k]: lane l -> m = l&15, k = (l>>4)*8 + r   (16x16x32 bf16)
//   B[k][n]: lane l -> n = l&15, k = (l>>4)*8 + r   (hiT/loT contiguous)
//   C[m][n]: lane l -> n = l&15, m = (l>>4)*4 + q
// P = ph+pl (bf16 hi/lo), V = vh+vl; out ≈ ph*vh + ph*vl + pl*vh.
// C_i = LR(src_i + max_j dst_j) >= row max (monotonic LR) -> one pass.
// ---------------------------------------------------------------------------
__global__ __launch_bounds__(256) void gat_attn_mfma(
    const unsigned int* __restrict__ mask32,
    const short* __restrict__ hiT, const short* __restrict__ loT,
    const float* __restrict__ vsrc, const float* __restrict__ vdst,
    float* __restrict__ out) {
  const int t = threadIdx.x, lane = t & 63, wid = t >> 6;
  // XCD swizzle: 1024 blocks, 128/XCD -> blocks sharing bh stay on one XCD
  const int blk = (blockIdx.x & 7) * 128 + (blockIdx.x >> 3);
  const int bh = blk >> 4;
  const int b  = bh >> 3;
  const int i0 = (blk & 15) * 64 + wid * 16;
  const int l15 = lane & 15, g4 = lane >> 4;
  const float LOG2E = 1.44269504088896340736f;

  const float* dstp = vdst + (size_t)bh * CN;

  float M = -INFINITY;
  #pragma unroll
  for (int s_ = 0; s_ < 16; ++s_) M = fmaxf(M, dstp[s_ * 64 + lane]);
  for (int mm = 32; mm; mm >>= 1) M = fmaxf(M, __shfl_xor(M, mm, 64));

  const float sv = vsrc[(size_t)bh * CN + i0 + l15];
  float c = sv + M;
  c = fmaxf(c, 0.2f * c);
  const float srcK = sv * LOG2E;
  const float cK   = c * LOG2E;

  f32x4 acc[4];
  #pragma unroll
  for (int g = 0; g < 4; ++g) acc[g] = (f32x4){0.f, 0.f, 0.f, 0.f};
  float lsum = 0.f;

  const unsigned int* mrow = mask32 + ((size_t)b * CN + i0 + l15) * 32;
  const short* Bh = hiT + ((size_t)bh * CFOUT + l15) * CN + g4 * 8;
  const short* Bl = loT + ((size_t)bh * CFOUT + l15) * CN + g4 * 8;

  for (int j0 = 0; j0 < CN; j0 += 32) {
    const float* dj = dstp + j0 + g4 * 8;
    float dK[8];
    {
      float4 d0 = *(const float4*)&dj[0];
      float4 d1 = *(const float4*)&dj[4];
      dK[0] = d0.x * LOG2E; dK[1] = d0.y * LOG2E; dK[2] = d0.z * LOG2E; dK[3] = d0.w * LOG2E;
      dK[4] = d1.x * LOG2E; dK[5] = d1.y * LOG2E; dK[6] = d1.z * LOG2E; dK[7] = d1.w * LOG2E;
    }
    s16x8 bhf[4], blf[4];
    #pragma unroll
    for (int g = 0; g < 4; ++g) {
      bhf[g] = *(const s16x8*)(Bh + (size_t)g * 16 * CN + j0);
      blf[g] = *(const s16x8*)(Bl + (size_t)g * 16 * CN + j0);
    }
    s16x8 ph, pl;
    {
      unsigned int word = mrow[j0 >> 5];
      unsigned int byte = (word >> (g4 * 8)) & 0xFFu;
      float ls = 0.f;
      #pragma unroll
      for (int r = 0; r < 8; ++r) {
        float s2 = srcK + dK[r];
        float lr = fmaxf(s2, 0.2f * s2);
        float e = exp2f(lr - cK);
        e = (byte & (1u << r)) ? e : 0.f;
        ls += e;
        short hi = f2bf(e);
        ph[r] = hi;
        pl[r] = f2bf(e - bf2f(hi));
      }
      lsum += ls;
    }
    #pragma unroll
    for (int g = 0; g < 4; ++g) {
      acc[g] = __builtin_amdgcn_mfma_f32_16x16x32_bf16(ph, bhf[g], acc[g], 0, 0, 0);
      acc[g] = __builtin_amdgcn_mfma_f32_16x16x32_bf16(ph, blf[g], acc[g], 0, 0, 0);
      acc[g] = __builtin_amdgcn_mfma_f32_16x16x32_bf16(pl, bhf[g], acc[g], 0, 0, 0);
    }
  }

  lsum += __shfl_xor(lsum, 16, 64);
  lsum += __shfl_xor(lsum, 32, 64);

  float linv[4];
  #pragma unroll
  for (int q = 0; q < 4; ++q)
    linv[q] = 1.0f / __shfl(lsum, g4 * 4 + q, 64);
  #pragma unroll
  for (int g = 0; g < 4; ++g)
    #pragma unroll
    for (int q = 0; q < 4; ++q) {
      int row = i0 + g4 * 4 + q;
      int col = g * 16 + l15;
      out[((size_t)bh * CN + row) * CFOUT + col] = acc[g][q] * linv[q];
    }
}

extern "C" void kernel_launch(void* const* d_in, const int* in_sizes, int n_in,
                              void* d_out, int out_size, void* d_ws, size_t ws_size,
                              hipStream_t stream) {
  const float* h     = (const float*)d_in[0];
  const int*   adj   = (const int*)d_in[1];
  const float* w     = (const float*)d_in[2];
  const float* a_src = (const float*)d_in[3];
  const float* a_dst = (const float*)d_in[4];
  float* out = (float*)d_out;

  // ws: hiT bf16 8MB | loT bf16 8MB | vsrc 256KB | vdst 256KB | mask 1MB
  char* p = (char*)d_ws;
  short* hiT = (short*)p;                 p += (size_t)64 * CFOUT * CN * 2;
  short* loT = (short*)p;                 p += (size_t)64 * CFOUT * CN * 2;
  float* vs  = (float*)p;                 p += (size_t)64 * CN * 4;
  float* vd  = (float*)p;                 p += (size_t)64 * CN * 4;
  unsigned long long* mask = (unsigned long long*)p;

  hipLaunchKernelGGL(gat_hprime_fused, dim3(64 * 16), dim3(256), 0, stream,
                     h, w, a_src, a_dst, hiT, loT, vs, vd);
  hipLaunchKernelGGL(pack_adj, dim3(CBS * CN * 16 / 4), dim3(256), 0, stream,
                     adj, mask);
  hipLaunchKernelGGL(gat_attn_mfma, dim3(64 * 16), dim3(256), 0, stream,
                     (const unsigned int*)mask, hiT, loT, vs, vd, out);
}

// Round 5
// 181.957 us; speedup vs baseline: 1.2629x; 1.2629x over previous
//
#include <hip/hip_runtime.h>
#include <math.h>

constexpr int CBS   = 8;
constexpr int CN    = 1024;
constexpr int CFIN  = 256;
constexpr int CNH   = 8;
constexpr int CFOUT = 64;

using f32x4 = __attribute__((ext_vector_type(4))) float;
using s16x8 = __attribute__((ext_vector_type(8))) short;

__device__ __forceinline__ short f2bf(float x) {
  __bf16 b = (__bf16)x;
  return __builtin_bit_cast(short, b);
}
__device__ __forceinline__ float bf2f(short s) {
  __bf16 b = __builtin_bit_cast(__bf16, s);
  return (float)b;
}
__device__ __forceinline__ unsigned int pkhi(float a, float b) {
  return (unsigned int)(unsigned short)f2bf(a) |
         ((unsigned int)(unsigned short)f2bf(b) << 16);
}

// ---------------------------------------------------------------------------
// Kernel 1 [VERIFIED round-2 code]: hp = h@w (f32 VALU), vsrc/vdst via tanh.
// ---------------------------------------------------------------------------
__global__ __launch_bounds__(256) void gat_hprime(
    const float* __restrict__ h, const float* __restrict__ w,
    const float* __restrict__ a_src, const float* __restrict__ a_dst,
    float* __restrict__ hp, float* __restrict__ vsrc, float* __restrict__ vdst) {
  __shared__ float w_s[CFIN * CFOUT];
  __shared__ float h_s[16 * CFIN];

  const int t    = threadIdx.x;
  const int blk  = blockIdx.x;
  const int tile = blk & 63;
  const int head = (blk >> 6) & 7;
  const int b    = blk >> 9;
  const int n0   = tile * 16;

  const float* wg = w + (size_t)head * CFIN * CFOUT;
  #pragma unroll
  for (int i = 0; i < 16; ++i) {
    int idx = (i * 256 + t) * 4;
    *(float4*)(w_s + idx) = *(const float4*)(wg + idx);
  }
  const float* hg = h + ((size_t)b * CN + n0) * CFIN;
  #pragma unroll
  for (int i = 0; i < 4; ++i) {
    int idx = (i * 256 + t) * 4;
    *(float4*)(h_s + idx) = *(const float4*)(hg + idx);
  }
  __syncthreads();

  const int o = t & 63, wid = t >> 6;
  float acc[4] = {0.f, 0.f, 0.f, 0.f};

  for (int k = 0; k < CFIN; k += 4) {
    float w0 = w_s[(k + 0) * CFOUT + o];
    float w1 = w_s[(k + 1) * CFOUT + o];
    float w2 = w_s[(k + 2) * CFOUT + o];
    float w3 = w_s[(k + 3) * CFOUT + o];
    #pragma unroll
    for (int q = 0; q < 4; ++q) {
      float4 hv = *(const float4*)(h_s + (wid * 4 + q) * CFIN + k);
      acc[q] = fmaf(hv.x, w0, acc[q]);
      acc[q] = fmaf(hv.y, w1, acc[q]);
      acc[q] = fmaf(hv.z, w2, acc[q]);
      acc[q] = fmaf(hv.w, w3, acc[q]);
    }
  }

  const size_t bh = (size_t)b * CNH + head;
  const float asv = a_src[head * CFOUT + o];
  const float adv = a_dst[head * CFOUT + o];
  #pragma unroll
  for (int q = 0; q < 4; ++q) {
    int n = n0 + wid * 4 + q;
    float v = acc[q];
    hp[(bh * CN + n) * CFOUT + o] = v;
    float tv = tanhf(v);
    float vs = tv * asv, vd = tv * adv;
    for (int mm = 32; mm; mm >>= 1) {
      vs += __shfl_xor(vs, mm, 64);
      vd += __shfl_xor(vd, mm, 64);
    }
    if (o == 0) { vsrc[bh * CN + n] = vs; vdst[bh * CN + n] = vd; }
  }
}

// ---------------------------------------------------------------------------
// Kernel 2 [VERIFIED round-3 code]: pack adj into bitmask, 1 bit per (b,i,j).
// ---------------------------------------------------------------------------
__global__ __launch_bounds__(256) void pack_adj(
    const int* __restrict__ adj, unsigned long long* __restrict__ mask) {
  const int t = threadIdx.x, lane = t & 63, w = t >> 6;
  const long long wid = (long long)blockIdx.x * 4 + w;   // (b*1024+i)*16 + jw
  const int jw = (int)(wid & 15);
  const long long bi = wid >> 4;
  int a = adj[bi * 1024 + jw * 64 + lane];
  unsigned long long m = __ballot(a > 0);
  if (lane == 0) mask[wid] = m;
}

// ---------------------------------------------------------------------------
// Kernel 3 [VERIFIED round-2 code]: hp f32 [bh][n][o] -> hi/lo bf16 T [bh][o][n]
// ---------------------------------------------------------------------------
__global__ __launch_bounds__(256) void split_T(
    const float* __restrict__ hp, short* __restrict__ hiT, short* __restrict__ loT) {
  __shared__ float s[64 * 65];
  const int blk = blockIdx.x;       // bh*16 + ntile
  const int nt = blk & 15, bh = blk >> 4;
  const int n0 = nt * 64;
  const int t = threadIdx.x;
  const float* src = hp + ((size_t)bh * CN + n0) * CFOUT;
  #pragma unroll
  for (int p = 0; p < 16; ++p) {
    int r = p * 4 + (t >> 6), o = t & 63;
    s[o * 65 + r] = src[(size_t)r * CFOUT + o];
  }
  __syncthreads();
  #pragma unroll
  for (int p = 0; p < 8; ++p) {
    int o = p * 8 + (t >> 5);
    int np = (t & 31) * 2;
    float v0 = s[o * 65 + np], v1 = s[o * 65 + np + 1];
    short h0 = f2bf(v0), h1 = f2bf(v1);
    short l0 = f2bf(v0 - bf2f(h0)), l1 = f2bf(v1 - bf2f(h1));
    size_t base = ((size_t)bh * CFOUT + o) * CN + n0 + np;   // even
    ((unsigned int*)hiT)[base >> 1] =
        (unsigned int)(unsigned short)h0 | ((unsigned int)(unsigned short)h1 << 16);
    ((unsigned int*)loT)[base >> 1] =
        (unsigned int)(unsigned short)l0 | ((unsigned int)(unsigned short)l1 << 16);
  }
}

// ---------------------------------------------------------------------------
// Kernel 4 [SUSPECT — round-4 attn verbatim]: masked-exp GEMM via MFMA.
// 512 blocks, 4 waves x 32 rows (f=0,1). P single-bf16; V hi/lo; l via
// ones-column MFMA (numerator/denominator share identical rounded weights).
// ---------------------------------------------------------------------------
__global__ __launch_bounds__(256) void gat_attn_mfma(
    const unsigned int* __restrict__ mask32,
    const short* __restrict__ hiT, const short* __restrict__ loT,
    const float* __restrict__ vsrc, const float* __restrict__ vdst,
    float* __restrict__ out) {
  const int t = threadIdx.x, lane = t & 63, wid = t >> 6;
  const int bid = blockIdx.x;
  const int blk = (bid & 7) * 64 + (bid >> 3);   // XCD swizzle: 8 bh per XCD
  const int bh = blk >> 3, b = bh >> 3;
  const int i0 = (blk & 7) * 128 + wid * 32;
  const int l15 = lane & 15, g4 = lane >> 4;
  const float LOG2E = 1.44269504088896340736f;

  const float* dstp = vdst + (size_t)bh * CN;

  float M = -INFINITY;
  #pragma unroll
  for (int s_ = 0; s_ < 16; ++s_) M = fmaxf(M, dstp[s_ * 64 + lane]);
  #pragma unroll
  for (int mm = 32; mm; mm >>= 1) M = fmaxf(M, __shfl_xor(M, mm, 64));

  float sA[2], sB[2];
  #pragma unroll
  for (int f = 0; f < 2; ++f) {
    float sv = vsrc[(size_t)bh * CN + i0 + f * 16 + l15];
    float c = sv + M;
    c = fmaxf(c, 0.2f * c);            // C_i = LR(src_i + M) >= row max
    float cK = c * LOG2E;
    sA[f] = sv * LOG2E - cK;
    sB[f] = 0.2f * (sv * LOG2E) - cK;
  }

  f32x4 acc[2][4], accL[2];
  #pragma unroll
  for (int f = 0; f < 2; ++f) {
    accL[f] = (f32x4){0.f, 0.f, 0.f, 0.f};
    #pragma unroll
    for (int g = 0; g < 4; ++g) acc[f][g] = (f32x4){0.f, 0.f, 0.f, 0.f};
  }

  s16x8 ones;
  {
    union { s16x8 v; unsigned int u[4]; } uo;
    unsigned int ow = (l15 == 0) ? 0x3F803F80u : 0u;
    uo.u[0] = uo.u[1] = uo.u[2] = uo.u[3] = ow;
    ones = uo.v;
  }

  const unsigned int* mr0 = mask32 + ((size_t)b * CN + i0 + l15) * 32;
  const unsigned int* mr1 = mr0 + 16 * 32;
  const short* Bh = hiT + ((size_t)bh * CFOUT + l15) * CN + g4 * 8;
  const short* Bl = loT + ((size_t)bh * CFOUT + l15) * CN + g4 * 8;
  const float K02 = 0.2f * LOG2E;

  for (int j0 = 0; j0 < CN; j0 += 32) {
    const float* dj = dstp + j0 + g4 * 8;
    float4 d0 = *(const float4*)&dj[0];
    float4 d1 = *(const float4*)&dj[4];
    float dK[8], dK2[8];
    dK[0] = d0.x * LOG2E; dK[1] = d0.y * LOG2E; dK[2] = d0.z * LOG2E; dK[3] = d0.w * LOG2E;
    dK[4] = d1.x * LOG2E; dK[5] = d1.y * LOG2E; dK[6] = d1.z * LOG2E; dK[7] = d1.w * LOG2E;
    dK2[0] = d0.x * K02; dK2[1] = d0.y * K02; dK2[2] = d0.z * K02; dK2[3] = d0.w * K02;
    dK2[4] = d1.x * K02; dK2[5] = d1.y * K02; dK2[6] = d1.z * K02; dK2[7] = d1.w * K02;

    s16x8 bhf[4], blf[4];
    #pragma unroll
    for (int g = 0; g < 4; ++g) {
      bhf[g] = *(const s16x8*)(Bh + (size_t)g * 16 * CN + j0);
      blf[g] = *(const s16x8*)(Bl + (size_t)g * 16 * CN + j0);
    }

    #pragma unroll
    for (int f = 0; f < 2; ++f) {
      unsigned int byte = ((f ? mr1 : mr0)[j0 >> 5] >> (g4 * 8)) & 0xFFu;
      float e[8];
      #pragma unroll
      for (int r = 0; r < 8; ++r) {
        float lr = fmaxf(sA[f] + dK[r], sB[f] + dK2[r]);
        lr = (byte & (1u << r)) ? lr : -500.f;
        e[r] = __builtin_amdgcn_exp2f(lr);
      }
      s16x8 ph;
      {
        union { s16x8 v; unsigned int u[4]; } up;
        up.u[0] = pkhi(e[0], e[1]);
        up.u[1] = pkhi(e[2], e[3]);
        up.u[2] = pkhi(e[4], e[5]);
        up.u[3] = pkhi(e[6], e[7]);
        ph = up.v;
      }
      accL[f] = __builtin_amdgcn_mfma_f32_16x16x32_bf16(ph, ones, accL[f], 0, 0, 0);
      #pragma unroll
      for (int g = 0; g < 4; ++g) {
        acc[f][g] = __builtin_amdgcn_mfma_f32_16x16x32_bf16(ph, bhf[g], acc[f][g], 0, 0, 0);
        acc[f][g] = __builtin_amdgcn_mfma_f32_16x16x32_bf16(ph, blf[g], acc[f][g], 0, 0, 0);
      }
    }
  }

  #pragma unroll
  for (int f = 0; f < 2; ++f) {
    float linv[4];
    #pragma unroll
    for (int q = 0; q < 4; ++q)
      linv[q] = 1.0f / __shfl(accL[f][q], g4 << 4, 64);   // l of row g4*4+q at lane g4*16
    #pragma unroll
    for (int g = 0; g < 4; ++g)
      #pragma unroll
      for (int q = 0; q < 4; ++q) {
        int row = i0 + f * 16 + g4 * 4 + q;
        int col = g * 16 + l15;
        out[((size_t)bh * CN + row) * CFOUT + col] = acc[f][g][q] * linv[q];
      }
  }
}

extern "C" void kernel_launch(void* const* d_in, const int* in_sizes, int n_in,
                              void* d_out, int out_size, void* d_ws, size_t ws_size,
                              hipStream_t stream) {
  const float* h     = (const float*)d_in[0];
  const int*   adj   = (const int*)d_in[1];
  const float* w     = (const float*)d_in[2];
  const float* a_src = (const float*)d_in[3];
  const float* a_dst = (const float*)d_in[4];
  float* out = (float*)d_out;

  // ws (round-2 footprint, proven to fit): hp 16MB | hiT 8MB | loT 8MB |
  // vsrc 256KB | vdst 256KB | mask 1MB
  char* p = (char*)d_ws;
  float* hp  = (float*)p;                 p += (size_t)64 * CN * CFOUT * 4;
  short* hiT = (short*)p;                 p += (size_t)64 * CFOUT * CN * 2;
  short* loT = (short*)p;                 p += (size_t)64 * CFOUT * CN * 2;
  float* vs  = (float*)p;                 p += (size_t)64 * CN * 4;
  float* vd  = (float*)p;                 p += (size_t)64 * CN * 4;
  unsigned long long* mask = (unsigned long long*)p;

  hipLaunchKernelGGL(gat_hprime, dim3(CBS * CNH * (CN / 16)), dim3(256), 0, stream,
                     h, w, a_src, a_dst, hp, vs, vd);
  hipLaunchKernelGGL(pack_adj, dim3(CBS * CN * 16 / 4), dim3(256), 0, stream,
                     adj, mask);
  hipLaunchKernelGGL(split_T, dim3(64 * 16), dim3(256), 0, stream,
                     hp, hiT, loT);
  hipLaunchKernelGGL(gat_attn_mfma, dim3(512), dim3(256), 0, stream,
                     (const unsigned int*)mask, hiT, loT, vs, vd, out);
}

// Round 6
// 149.552 us; speedup vs baseline: 1.5366x; 1.2167x over previous
//
#include <hip/hip_runtime.h>
#include <math.h>

constexpr int CBS   = 8;
constexpr int CN    = 1024;
constexpr int CFIN  = 256;
constexpr int CNH   = 8;
constexpr int CFOUT = 64;

using f32x4 = __attribute__((ext_vector_type(4))) float;
using s16x8 = __attribute__((ext_vector_type(8))) short;

__device__ __forceinline__ short f2bf(float x) {
  __bf16 b = (__bf16)x;
  return __builtin_bit_cast(short, b);
}
__device__ __forceinline__ float bf2f(short s) {
  __bf16 b = __builtin_bit_cast(__bf16, s);
  return (float)b;
}
__device__ __forceinline__ unsigned int pkhi(float a, float b) {
  return (unsigned int)(unsigned short)f2bf(a) |
         ((unsigned int)(unsigned short)f2bf(b) << 16);
}

// ---------------------------------------------------------------------------
// conv_h [round-4 verbatim]: h f32 [b][n][256] -> hh/hl bf16-pair u32 words.
// ---------------------------------------------------------------------------
__global__ __launch_bounds__(256) void conv_h(
    const float* __restrict__ h, unsigned int* __restrict__ hh,
    unsigned int* __restrict__ hl) {
  size_t i = (size_t)blockIdx.x * 256 + threadIdx.x;
  const float4* src = (const float4*)(h + i * 8);
  float4 a = src[0], b = src[1];
  float v[8] = {a.x, a.y, a.z, a.w, b.x, b.y, b.z, b.w};
  unsigned int hw[4], lw[4];
  #pragma unroll
  for (int p = 0; p < 4; ++p) {
    float x0 = v[2 * p], x1 = v[2 * p + 1];
    short h0 = f2bf(x0), h1 = f2bf(x1);
    hw[p] = (unsigned int)(unsigned short)h0 | ((unsigned int)(unsigned short)h1 << 16);
    lw[p] = pkhi(x0 - bf2f(h0), x1 - bf2f(h1));
  }
  ((uint4*)hh)[i] = make_uint4(hw[0], hw[1], hw[2], hw[3]);
  ((uint4*)hl)[i] = make_uint4(lw[0], lw[1], lw[2], lw[3]);
}

// ---------------------------------------------------------------------------
// conv_w [round-4 verbatim]: w f32 [head][k][64] -> wh/wl transposed [head][o][128w]
// ---------------------------------------------------------------------------
__global__ __launch_bounds__(256) void conv_w(
    const float* __restrict__ w, unsigned int* __restrict__ wh,
    unsigned int* __restrict__ wl) {
  const int head = blockIdx.x, t = threadIdx.x;
  const int o = t & 63, kc = (t >> 6) * 64;
  const float* wg = w + (size_t)head * CFIN * CFOUT;
  unsigned int* dh = wh + ((size_t)head * 64 + o) * 128 + (kc >> 1);
  unsigned int* dl = wl + ((size_t)head * 64 + o) * 128 + (kc >> 1);
  #pragma unroll 4
  for (int k2 = 0; k2 < 32; ++k2) {
    int k = kc + k2 * 2;
    float x0 = wg[(size_t)k * 64 + o], x1 = wg[(size_t)(k + 1) * 64 + o];
    short h0 = f2bf(x0), h1 = f2bf(x1);
    dh[k2] = (unsigned int)(unsigned short)h0 | ((unsigned int)(unsigned short)h1 << 16);
    dl[k2] = pkhi(x0 - bf2f(h0), x1 - bf2f(h1));
  }
}

// ---------------------------------------------------------------------------
// pack_adj [VERIFIED round-3 code]
// ---------------------------------------------------------------------------
__global__ __launch_bounds__(256) void pack_adj(
    const int* __restrict__ adj, unsigned long long* __restrict__ mask) {
  const int t = threadIdx.x, lane = t & 63, w = t >> 6;
  const long long wid = (long long)blockIdx.x * 4 + w;   // (b*1024+i)*16 + jw
  const int jw = (int)(wid & 15);
  const long long bi = wid >> 4;
  int a = adj[bi * 1024 + jw * 64 + lane];
  unsigned long long m = __ballot(a > 0);
  if (lane == 0) mask[wid] = m;
}

// ---------------------------------------------------------------------------
// hprime_mfma_lite [round-4 MFMA core verbatim; epilogue = bare f32 store
// mirroring attn's VERIFIED C-write]: hp[bh][n][o] = h@w, hi/lo 3-MFMA split.
// ---------------------------------------------------------------------------
__global__ __launch_bounds__(256) void hprime_mfma_lite(
    const unsigned int* __restrict__ hh, const unsigned int* __restrict__ hl,
    const unsigned int* __restrict__ wh, const unsigned int* __restrict__ wl,
    float* __restrict__ hp) {
  const int t = threadIdx.x, lane = t & 63, wid = t >> 6;
  const int bid = blockIdx.x;
  const int blk = (bid & 7) * 64 + (bid >> 3);   // XCD swizzle: one b per XCD
  const int bh = blk >> 3, head = bh & 7, b = bh >> 3;
  const int row0 = (blk & 7) * 128 + wid * 32;
  const int l15 = lane & 15, g4 = lane >> 4;

  const unsigned int* A0 = hh + ((size_t)b * CN + row0 + l15) * 128 + g4 * 4;
  const unsigned int* A1 = hl + ((size_t)b * CN + row0 + l15) * 128 + g4 * 4;
  const unsigned int* B0 = wh + ((size_t)head * 64 + l15) * 128 + g4 * 4;
  const unsigned int* B1 = wl + ((size_t)head * 64 + l15) * 128 + g4 * 4;

  f32x4 acc[2][4];
  #pragma unroll
  for (int f = 0; f < 2; ++f)
    #pragma unroll
    for (int g = 0; g < 4; ++g) acc[f][g] = (f32x4){0.f, 0.f, 0.f, 0.f};

  for (int kw = 0; kw < 128; kw += 16) {   // 32 k per iter
    s16x8 ah[2], al[2], bhf[4], blf[4];
    #pragma unroll
    for (int f = 0; f < 2; ++f) {
      ah[f] = *(const s16x8*)(A0 + (size_t)f * 16 * 128 + kw);
      al[f] = *(const s16x8*)(A1 + (size_t)f * 16 * 128 + kw);
    }
    #pragma unroll
    for (int g = 0; g < 4; ++g) {
      bhf[g] = *(const s16x8*)(B0 + (size_t)g * 16 * 128 + kw);
      blf[g] = *(const s16x8*)(B1 + (size_t)g * 16 * 128 + kw);
    }
    #pragma unroll
    for (int f = 0; f < 2; ++f)
      #pragma unroll
      for (int g = 0; g < 4; ++g) {
        acc[f][g] = __builtin_amdgcn_mfma_f32_16x16x32_bf16(ah[f], bhf[g], acc[f][g], 0, 0, 0);
        acc[f][g] = __builtin_amdgcn_mfma_f32_16x16x32_bf16(ah[f], blf[g], acc[f][g], 0, 0, 0);
        acc[f][g] = __builtin_amdgcn_mfma_f32_16x16x32_bf16(al[f], bhf[g], acc[f][g], 0, 0, 0);
      }
  }

  #pragma unroll
  for (int f = 0; f < 2; ++f)
    #pragma unroll
    for (int g = 0; g < 4; ++g)
      #pragma unroll
      for (int q = 0; q < 4; ++q) {
        int row = row0 + f * 16 + g4 * 4 + q;
        int col = g * 16 + l15;
        hp[((size_t)bh * CN + row) * CFOUT + col] = acc[f][g][q];
      }
}

// ---------------------------------------------------------------------------
// vsd [NEW, round-1 verified pattern]: vsrc/vdst from hp.
// 4096 blocks x 4 waves x 4 rows; lane = o.
// ---------------------------------------------------------------------------
__global__ __launch_bounds__(256) void vsd(
    const float* __restrict__ hp, const float* __restrict__ a_src,
    const float* __restrict__ a_dst, float* __restrict__ vsrc,
    float* __restrict__ vdst) {
  const int t = threadIdx.x, lane = t & 63, wid = t >> 6;
  const int gr = blockIdx.x * 16 + wid * 4;      // global row (bh*1024+n), 4 rows
  const int head = (gr >> 10) & 7;
  const float asv = a_src[head * CFOUT + lane];
  const float adv = a_dst[head * CFOUT + lane];
  #pragma unroll
  for (int q = 0; q < 4; ++q) {
    size_t row = (size_t)gr + q;
    float v = hp[row * CFOUT + lane];
    float tv = tanhf(v);
    float vs = tv * asv, vd = tv * adv;
    for (int mm = 32; mm; mm >>= 1) {
      vs += __shfl_xor(vs, mm, 64);
      vd += __shfl_xor(vd, mm, 64);
    }
    if (lane == 0) { vsrc[row] = vs; vdst[row] = vd; }
  }
}

// ---------------------------------------------------------------------------
// split_T [VERIFIED round-2 code]: hp f32 [bh][n][o] -> hi/lo bf16 T [bh][o][n]
// ---------------------------------------------------------------------------
__global__ __launch_bounds__(256) void split_T(
    const float* __restrict__ hp, short* __restrict__ hiT, short* __restrict__ loT) {
  __shared__ float s[64 * 65];
  const int blk = blockIdx.x;       // bh*16 + ntile
  const int nt = blk & 15, bh = blk >> 4;
  const int n0 = nt * 64;
  const int t = threadIdx.x;
  const float* src = hp + ((size_t)bh * CN + n0) * CFOUT;
  #pragma unroll
  for (int p = 0; p < 16; ++p) {
    int r = p * 4 + (t >> 6), o = t & 63;
    s[o * 65 + r] = src[(size_t)r * CFOUT + o];
  }
  __syncthreads();
  #pragma unroll
  for (int p = 0; p < 8; ++p) {
    int o = p * 8 + (t >> 5);
    int np = (t & 31) * 2;
    float v0 = s[o * 65 + np], v1 = s[o * 65 + np + 1];
    short h0 = f2bf(v0), h1 = f2bf(v1);
    short l0 = f2bf(v0 - bf2f(h0)), l1 = f2bf(v1 - bf2f(h1));
    size_t base = ((size_t)bh * CFOUT + o) * CN + n0 + np;   // even
    ((unsigned int*)hiT)[base >> 1] =
        (unsigned int)(unsigned short)h0 | ((unsigned int)(unsigned short)h1 << 16);
    ((unsigned int*)loT)[base >> 1] =
        (unsigned int)(unsigned short)l0 | ((unsigned int)(unsigned short)l1 << 16);
  }
}

// ---------------------------------------------------------------------------
// attn [VERIFIED round-4/5 code]: masked-exp GEMM via MFMA.
// ---------------------------------------------------------------------------
__global__ __launch_bounds__(256) void gat_attn_mfma(
    const unsigned int* __restrict__ mask32,
    const short* __restrict__ hiT, const short* __restrict__ loT,
    const float* __restrict__ vsrc, const float* __restrict__ vdst,
    float* __restrict__ out) {
  const int t = threadIdx.x, lane = t & 63, wid = t >> 6;
  const int bid = blockIdx.x;
  const int blk = (bid & 7) * 64 + (bid >> 3);   // XCD swizzle: 8 bh per XCD
  const int bh = blk >> 3, b = bh >> 3;
  const int i0 = (blk & 7) * 128 + wid * 32;
  const int l15 = lane & 15, g4 = lane >> 4;
  const float LOG2E = 1.44269504088896340736f;

  const float* dstp = vdst + (size_t)bh * CN;

  float M = -INFINITY;
  #pragma unroll
  for (int s_ = 0; s_ < 16; ++s_) M = fmaxf(M, dstp[s_ * 64 + lane]);
  #pragma unroll
  for (int mm = 32; mm; mm >>= 1) M = fmaxf(M, __shfl_xor(M, mm, 64));

  float sA[2], sB[2];
  #pragma unroll
  for (int f = 0; f < 2; ++f) {
    float sv = vsrc[(size_t)bh * CN + i0 + f * 16 + l15];
    float c = sv + M;
    c = fmaxf(c, 0.2f * c);            // C_i = LR(src_i + M) >= row max
    float cK = c * LOG2E;
    sA[f] = sv * LOG2E - cK;
    sB[f] = 0.2f * (sv * LOG2E) - cK;
  }

  f32x4 acc[2][4], accL[2];
  #pragma unroll
  for (int f = 0; f < 2; ++f) {
    accL[f] = (f32x4){0.f, 0.f, 0.f, 0.f};
    #pragma unroll
    for (int g = 0; g < 4; ++g) acc[f][g] = (f32x4){0.f, 0.f, 0.f, 0.f};
  }

  s16x8 ones;
  {
    union { s16x8 v; unsigned int u[4]; } uo;
    unsigned int ow = (l15 == 0) ? 0x3F803F80u : 0u;
    uo.u[0] = uo.u[1] = uo.u[2] = uo.u[3] = ow;
    ones = uo.v;
  }

  const unsigned int* mr0 = mask32 + ((size_t)b * CN + i0 + l15) * 32;
  const unsigned int* mr1 = mr0 + 16 * 32;
  const short* Bh = hiT + ((size_t)bh * CFOUT + l15) * CN + g4 * 8;
  const short* Bl = loT + ((size_t)bh * CFOUT + l15) * CN + g4 * 8;
  const float K02 = 0.2f * LOG2E;

  for (int j0 = 0; j0 < CN; j0 += 32) {
    const float* dj = dstp + j0 + g4 * 8;
    float4 d0 = *(const float4*)&dj[0];
    float4 d1 = *(const float4*)&dj[4];
    float dK[8], dK2[8];
    dK[0] = d0.x * LOG2E; dK[1] = d0.y * LOG2E; dK[2] = d0.z * LOG2E; dK[3] = d0.w * LOG2E;
    dK[4] = d1.x * LOG2E; dK[5] = d1.y * LOG2E; dK[6] = d1.z * LOG2E; dK[7] = d1.w * LOG2E;
    dK2[0] = d0.x * K02; dK2[1] = d0.y * K02; dK2[2] = d0.z * K02; dK2[3] = d0.w * K02;
    dK2[4] = d1.x * K02; dK2[5] = d1.y * K02; dK2[6] = d1.z * K02; dK2[7] = d1.w * K02;

    s16x8 bhf[4], blf[4];
    #pragma unroll
    for (int g = 0; g < 4; ++g) {
      bhf[g] = *(const s16x8*)(Bh + (size_t)g * 16 * CN + j0);
      blf[g] = *(const s16x8*)(Bl + (size_t)g * 16 * CN + j0);
    }

    #pragma unroll
    for (int f = 0; f < 2; ++f) {
      unsigned int byte = ((f ? mr1 : mr0)[j0 >> 5] >> (g4 * 8)) & 0xFFu;
      float e[8];
      #pragma unroll
      for (int r = 0; r < 8; ++r) {
        float lr = fmaxf(sA[f] + dK[r], sB[f] + dK2[r]);
        lr = (byte & (1u << r)) ? lr : -500.f;
        e[r] = __builtin_amdgcn_exp2f(lr);
      }
      s16x8 ph;
      {
        union { s16x8 v; unsigned int u[4]; } up;
        up.u[0] = pkhi(e[0], e[1]);
        up.u[1] = pkhi(e[2], e[3]);
        up.u[2] = pkhi(e[4], e[5]);
        up.u[3] = pkhi(e[6], e[7]);
        ph = up.v;
      }
      accL[f] = __builtin_amdgcn_mfma_f32_16x16x32_bf16(ph, ones, accL[f], 0, 0, 0);
      #pragma unroll
      for (int g = 0; g < 4; ++g) {
        acc[f][g] = __builtin_amdgcn_mfma_f32_16x16x32_bf16(ph, bhf[g], acc[f][g], 0, 0, 0);
        acc[f][g] = __builtin_amdgcn_mfma_f32_16x16x32_bf16(ph, blf[g], acc[f][g], 0, 0, 0);
      }
    }
  }

  #pragma unroll
  for (int f = 0; f < 2; ++f) {
    float linv[4];
    #pragma unroll
    for (int q = 0; q < 4; ++q)
      linv[q] = 1.0f / __shfl(accL[f][q], g4 << 4, 64);   // l of row g4*4+q at lane g4*16
    #pragma unroll
    for (int g = 0; g < 4; ++g)
      #pragma unroll
      for (int q = 0; q < 4; ++q) {
        int row = i0 + f * 16 + g4 * 4 + q;
        int col = g * 16 + l15;
        out[((size_t)bh * CN + row) * CFOUT + col] = acc[f][g][q] * linv[q];
      }
  }
}

extern "C" void kernel_launch(void* const* d_in, const int* in_sizes, int n_in,
                              void* d_out, int out_size, void* d_ws, size_t ws_size,
                              hipStream_t stream) {
  const float* h     = (const float*)d_in[0];
  const int*   adj   = (const int*)d_in[1];
  const float* w     = (const float*)d_in[2];
  const float* a_src = (const float*)d_in[3];
  const float* a_dst = (const float*)d_in[4];
  float* out = (float*)d_out;

  // ws layout (33.5MB total — exactly the round-2-proven footprint), with
  // TEMPORAL aliasing (same-stream ordering guarantees safety):
  //   [ 0M..16M)  hp f32
  //   [16M..24M)  hh 4M | hl 4M   --later-->  hiT 8M   (split_T after lite)
  //   [24M..32M)  loT 8M
  //   [32M..32.5M) vsrc | vdst
  //   [32.5M..33.5M) wh 256K | wl 256K --later--> mask 1M (pack_adj after lite)
  char* p = (char*)d_ws;
  float* hp  = (float*)p;
  unsigned int* hh = (unsigned int*)(p + (size_t)(16u << 20));
  unsigned int* hl = (unsigned int*)(p + (size_t)(20u << 20));
  short* hiT = (short*)(p + (size_t)(16u << 20));
  short* loT = (short*)(p + (size_t)(24u << 20));
  float* vs  = (float*)(p + (size_t)(32u << 20));
  float* vd  = (float*)(p + (size_t)(32u << 20) + (256u << 10));
  unsigned int* wh = (unsigned int*)(p + (size_t)(32u << 20) + (512u << 10));
  unsigned int* wl = (unsigned int*)(p + (size_t)(32u << 20) + (768u << 10));
  unsigned long long* mask = (unsigned long long*)(p + (size_t)(32u << 20) + (512u << 10));

  hipLaunchKernelGGL(conv_h, dim3(1024), dim3(256), 0, stream, h, hh, hl);
  hipLaunchKernelGGL(conv_w, dim3(8), dim3(256), 0, stream, w, wh, wl);
  hipLaunchKernelGGL(hprime_mfma_lite, dim3(512), dim3(256), 0, stream,
                     hh, hl, wh, wl, hp);
  hipLaunchKernelGGL(vsd, dim3(4096), dim3(256), 0, stream, hp, a_src, a_dst, vs, vd);
  hipLaunchKernelGGL(split_T, dim3(64 * 16), dim3(256), 0, stream, hp, hiT, loT);
  hipLaunchKernelGGL(pack_adj, dim3(CBS * CN * 16 / 4), dim3(256), 0, stream,
                     adj, mask);
  hipLaunchKernelGGL(gat_attn_mfma, dim3(512), dim3(256), 0, stream,
                     (const unsigned int*)mask, hiT, loT, vs, vd, out);
}

// Round 8
// 137.408 us; speedup vs baseline: 1.6724x; 1.0884x over previous
//
#include <hip/hip_runtime.h>
#include <math.h>

constexpr int CBS   = 8;
constexpr int CN    = 1024;
constexpr int CFIN  = 256;
constexpr int CNH   = 8;
constexpr int CFOUT = 64;

using f32x4 = __attribute__((ext_vector_type(4))) float;
using s16x8 = __attribute__((ext_vector_type(8))) short;

__device__ __forceinline__ short f2bf(float x) {
  __bf16 b = (__bf16)x;
  return __builtin_bit_cast(short, b);
}
__device__ __forceinline__ float bf2f(short s) {
  __bf16 b = __builtin_bit_cast(__bf16, s);
  return (float)b;
}
__device__ __forceinline__ unsigned int pkhi(float a, float b) {
  return (unsigned int)(unsigned short)f2bf(a) |
         ((unsigned int)(unsigned short)f2bf(b) << 16);
}

// ---------------------------------------------------------------------------
// prep = conv_h [verified] (blocks 0..1023) + conv_w [verified] (blocks 1024..1031)
// ---------------------------------------------------------------------------
__global__ __launch_bounds__(256) void prep(
    const float* __restrict__ h, const float* __restrict__ w,
    unsigned int* __restrict__ hh, unsigned int* __restrict__ hl,
    unsigned int* __restrict__ wh, unsigned int* __restrict__ wl) {
  const int blk = blockIdx.x, t = threadIdx.x;
  if (blk < 1024) {
    size_t i = (size_t)blk * 256 + t;
    const float4* src = (const float4*)(h + i * 8);
    float4 a = src[0], b = src[1];
    float v[8] = {a.x, a.y, a.z, a.w, b.x, b.y, b.z, b.w};
    unsigned int hw[4], lw[4];
    #pragma unroll
    for (int p = 0; p < 4; ++p) {
      float x0 = v[2 * p], x1 = v[2 * p + 1];
      short h0 = f2bf(x0), h1 = f2bf(x1);
      hw[p] = (unsigned int)(unsigned short)h0 | ((unsigned int)(unsigned short)h1 << 16);
      lw[p] = pkhi(x0 - bf2f(h0), x1 - bf2f(h1));
    }
    ((uint4*)hh)[i] = make_uint4(hw[0], hw[1], hw[2], hw[3]);
    ((uint4*)hl)[i] = make_uint4(lw[0], lw[1], lw[2], lw[3]);
  } else {
    const int head = blk - 1024;
    const int o = t & 63, kc = (t >> 6) * 64;
    const float* wg = w + (size_t)head * CFIN * CFOUT;
    unsigned int* dh = wh + ((size_t)head * 64 + o) * 128 + (kc >> 1);
    unsigned int* dl = wl + ((size_t)head * 64 + o) * 128 + (kc >> 1);
    #pragma unroll 4
    for (int k2 = 0; k2 < 32; ++k2) {
      int k = kc + k2 * 2;
      float x0 = wg[(size_t)k * 64 + o], x1 = wg[(size_t)(k + 1) * 64 + o];
      short h0 = f2bf(x0), h1 = f2bf(x1);
      dh[k2] = (unsigned int)(unsigned short)h0 | ((unsigned int)(unsigned short)h1 << 16);
      dl[k2] = pkhi(x0 - bf2f(h0), x1 - bf2f(h1));
    }
  }
}

// ---------------------------------------------------------------------------
// hprime_mfma_lite [VERIFIED round-6]: hp = h@w via hi/lo 3-MFMA split.
// ---------------------------------------------------------------------------
__global__ __launch_bounds__(256) void hprime_mfma_lite(
    const unsigned int* __restrict__ hh, const unsigned int* __restrict__ hl,
    const unsigned int* __restrict__ wh, const unsigned int* __restrict__ wl,
    float* __restrict__ hp) {
  const int t = threadIdx.x, lane = t & 63, wid = t >> 6;
  const int bid = blockIdx.x;
  const int blk = (bid & 7) * 64 + (bid >> 3);   // XCD swizzle: one b per XCD
  const int bh = blk >> 3, head = bh & 7, b = bh >> 3;
  const int row0 = (blk & 7) * 128 + wid * 32;
  const int l15 = lane & 15, g4 = lane >> 4;

  const unsigned int* A0 = hh + ((size_t)b * CN + row0 + l15) * 128 + g4 * 4;
  const unsigned int* A1 = hl + ((size_t)b * CN + row0 + l15) * 128 + g4 * 4;
  const unsigned int* B0 = wh + ((size_t)head * 64 + l15) * 128 + g4 * 4;
  const unsigned int* B1 = wl + ((size_t)head * 64 + l15) * 128 + g4 * 4;

  f32x4 acc[2][4];
  #pragma unroll
  for (int f = 0; f < 2; ++f)
    #pragma unroll
    for (int g = 0; g < 4; ++g) acc[f][g] = (f32x4){0.f, 0.f, 0.f, 0.f};

  for (int kw = 0; kw < 128; kw += 16) {   // 32 k per iter
    s16x8 ah[2], al[2], bhf[4], blf[4];
    #pragma unroll
    for (int f = 0; f < 2; ++f) {
      ah[f] = *(const s16x8*)(A0 + (size_t)f * 16 * 128 + kw);
      al[f] = *(const s16x8*)(A1 + (size_t)f * 16 * 128 + kw);
    }
    #pragma unroll
    for (int g = 0; g < 4; ++g) {
      bhf[g] = *(const s16x8*)(B0 + (size_t)g * 16 * 128 + kw);
      blf[g] = *(const s16x8*)(B1 + (size_t)g * 16 * 128 + kw);
    }
    #pragma unroll
    for (int f = 0; f < 2; ++f)
      #pragma unroll
      for (int g = 0; g < 4; ++g) {
        acc[f][g] = __builtin_amdgcn_mfma_f32_16x16x32_bf16(ah[f], bhf[g], acc[f][g], 0, 0, 0);
        acc[f][g] = __builtin_amdgcn_mfma_f32_16x16x32_bf16(ah[f], blf[g], acc[f][g], 0, 0, 0);
        acc[f][g] = __builtin_amdgcn_mfma_f32_16x16x32_bf16(al[f], bhf[g], acc[f][g], 0, 0, 0);
      }
  }

  #pragma unroll
  for (int f = 0; f < 2; ++f)
    #pragma unroll
    for (int g = 0; g < 4; ++g)
      #pragma unroll
      for (int q = 0; q < 4; ++q) {
        int row = row0 + f * 16 + g4 * 4 + q;
        int col = g * 16 + l15;
        hp[((size_t)bh * CN + row) * CFOUT + col] = acc[f][g][q];
      }
}

// ---------------------------------------------------------------------------
// mid = split_T [verified] + vsd [verified pattern] (blocks 0..1023)
//     + pack_adj [verified] (blocks 1024..34815 -> wid 0..131071)
// FIX vs round 7: pack path needs 32768 blocks (4 u64 words each), not 8192.
// ---------------------------------------------------------------------------
__global__ __launch_bounds__(256) void mid(
    const float* __restrict__ hp, const float* __restrict__ a_src,
    const float* __restrict__ a_dst, const int* __restrict__ adj,
    short* __restrict__ hiT, short* __restrict__ loT,
    float* __restrict__ vsrc, float* __restrict__ vdst,
    unsigned long long* __restrict__ mask) {
  __shared__ float s[64 * 65];
  const int blk = blockIdx.x, t = threadIdx.x;
  if (blk >= 1024) {               // pack_adj path (block-uniform branch)
    const int lane = t & 63, w = t >> 6;
    const long long wid = (long long)(blk - 1024) * 4 + w;  // (b*1024+i)*16+jw
    const int jw = (int)(wid & 15);
    const long long bi = wid >> 4;
    int a = adj[bi * 1024 + jw * 64 + lane];
    unsigned long long m = __ballot(a > 0);
    if (lane == 0) mask[wid] = m;
    return;
  }
  const int nt = blk & 15, bh = blk >> 4;
  const int n0 = nt * 64;
  const float* src = hp + ((size_t)bh * CN + n0) * CFOUT;
  #pragma unroll
  for (int p = 0; p < 16; ++p) {
    int r = p * 4 + (t >> 6), o = t & 63;
    s[o * 65 + r] = src[(size_t)r * CFOUT + o];
  }
  __syncthreads();
  // split_T writes [verified round-2]
  #pragma unroll
  for (int p = 0; p < 8; ++p) {
    int o = p * 8 + (t >> 5);
    int np = (t & 31) * 2;
    float v0 = s[o * 65 + np], v1 = s[o * 65 + np + 1];
    short h0 = f2bf(v0), h1 = f2bf(v1);
    short l0 = f2bf(v0 - bf2f(h0)), l1 = f2bf(v1 - bf2f(h1));
    size_t base = ((size_t)bh * CFOUT + o) * CN + n0 + np;   // even
    ((unsigned int*)hiT)[base >> 1] =
        (unsigned int)(unsigned short)h0 | ((unsigned int)(unsigned short)h1 << 16);
    ((unsigned int*)loT)[base >> 1] =
        (unsigned int)(unsigned short)l0 | ((unsigned int)(unsigned short)l1 << 16);
  }
  // vsd from the same LDS tile: wave wid handles rows wid*16..wid*16+15
  {
    const int lane = t & 63, wid = t >> 6;
    const int head = bh & 7;
    const float asv = a_src[head * CFOUT + lane];
    const float adv = a_dst[head * CFOUT + lane];
    #pragma unroll
    for (int q = 0; q < 16; ++q) {
      int r = wid * 16 + q;
      float v = s[lane * 65 + r];      // (lane+r)%32 banks: 2-way, free
      float tv = tanhf(v);
      float vsx = tv * asv, vdx = tv * adv;
      for (int mm = 32; mm; mm >>= 1) {
        vsx += __shfl_xor(vsx, mm, 64);
        vdx += __shfl_xor(vdx, mm, 64);
      }
      if (lane == 0) {
        vsrc[(size_t)bh * CN + n0 + r] = vsx;
        vdst[(size_t)bh * CN + n0 + r] = vdx;
      }
    }
  }
}

// ---------------------------------------------------------------------------
// attn [round-6 verified per-wave structure + j-split across wave groups]:
// 512 blocks x 512 thr (8 waves). Group 0 (waves 0-3): j in [0,512);
// group 1 (waves 4-7): j in [512,1024). Same 128 rows; partial (acc, accL)
// merged via LDS (C_i bound uses global M, so scales match exactly).
// ---------------------------------------------------------------------------
__global__ __launch_bounds__(512) void gat_attn_mfma(
    const unsigned int* __restrict__ mask32,
    const short* __restrict__ hiT, const short* __restrict__ loT,
    const float* __restrict__ vsrc, const float* __restrict__ vdst,
    float* __restrict__ out) {
  __shared__ float ldsm[32 * 256 + 8 * 256];   // 40KB partial merge
  const int t = threadIdx.x, lane = t & 63, wid = t >> 6;
  const int w4 = wid & 3, grp = wid >> 2;
  const int bid = blockIdx.x;
  const int blk = (bid & 7) * 64 + (bid >> 3);   // XCD swizzle: 8 bh per XCD
  const int bh = blk >> 3, b = bh >> 3;
  const int i0 = (blk & 7) * 128 + w4 * 32;
  const int l15 = lane & 15, g4 = lane >> 4;
  const float LOG2E = 1.44269504088896340736f;

  const float* dstp = vdst + (size_t)bh * CN;

  float M = -INFINITY;
  #pragma unroll
  for (int s_ = 0; s_ < 16; ++s_) M = fmaxf(M, dstp[s_ * 64 + lane]);
  #pragma unroll
  for (int mm = 32; mm; mm >>= 1) M = fmaxf(M, __shfl_xor(M, mm, 64));

  float sA[2], sB[2];
  #pragma unroll
  for (int f = 0; f < 2; ++f) {
    float sv = vsrc[(size_t)bh * CN + i0 + f * 16 + l15];
    float c = sv + M;
    c = fmaxf(c, 0.2f * c);            // C_i = LR(src_i + M) >= row max
    float cK = c * LOG2E;
    sA[f] = sv * LOG2E - cK;
    sB[f] = 0.2f * (sv * LOG2E) - cK;
  }

  f32x4 acc[2][4], accL[2];
  #pragma unroll
  for (int f = 0; f < 2; ++f) {
    accL[f] = (f32x4){0.f, 0.f, 0.f, 0.f};
    #pragma unroll
    for (int g = 0; g < 4; ++g) acc[f][g] = (f32x4){0.f, 0.f, 0.f, 0.f};
  }

  s16x8 ones;
  {
    union { s16x8 v; unsigned int u[4]; } uo;
    unsigned int ow = (l15 == 0) ? 0x3F803F80u : 0u;
    uo.u[0] = uo.u[1] = uo.u[2] = uo.u[3] = ow;
    ones = uo.v;
  }

  const unsigned int* mr0 = mask32 + ((size_t)b * CN + i0 + l15) * 32;
  const unsigned int* mr1 = mr0 + 16 * 32;
  const short* Bh = hiT + ((size_t)bh * CFOUT + l15) * CN + g4 * 8;
  const short* Bl = loT + ((size_t)bh * CFOUT + l15) * CN + g4 * 8;
  const float K02 = 0.2f * LOG2E;
  const int jbase = grp * 512;

  for (int j0 = jbase; j0 < jbase + 512; j0 += 32) {
    const float* dj = dstp + j0 + g4 * 8;
    float4 d0 = *(const float4*)&dj[0];
    float4 d1 = *(const float4*)&dj[4];
    float dK[8], dK2[8];
    dK[0] = d0.x * LOG2E; dK[1] = d0.y * LOG2E; dK[2] = d0.z * LOG2E; dK[3] = d0.w * LOG2E;
    dK[4] = d1.x * LOG2E; dK[5] = d1.y * LOG2E; dK[6] = d1.z * LOG2E; dK[7] = d1.w * LOG2E;
    dK2[0] = d0.x * K02; dK2[1] = d0.y * K02; dK2[2] = d0.z * K02; dK2[3] = d0.w * K02;
    dK2[4] = d1.x * K02; dK2[5] = d1.y * K02; dK2[6] = d1.z * K02; dK2[7] = d1.w * K02;

    s16x8 bhf[4], blf[4];
    #pragma unroll
    for (int g = 0; g < 4; ++g) {
      bhf[g] = *(const s16x8*)(Bh + (size_t)g * 16 * CN + j0);
      blf[g] = *(const s16x8*)(Bl + (size_t)g * 16 * CN + j0);
    }

    #pragma unroll
    for (int f = 0; f < 2; ++f) {
      unsigned int byte = ((f ? mr1 : mr0)[j0 >> 5] >> (g4 * 8)) & 0xFFu;
      float e[8];
      #pragma unroll
      for (int r = 0; r < 8; ++r) {
        float lr = fmaxf(sA[f] + dK[r], sB[f] + dK2[r]);
        lr = (byte & (1u << r)) ? lr : -500.f;
        e[r] = __builtin_amdgcn_exp2f(lr);
      }
      s16x8 ph;
      {
        union { s16x8 v; unsigned int u[4]; } up;
        up.u[0] = pkhi(e[0], e[1]);
        up.u[1] = pkhi(e[2], e[3]);
        up.u[2] = pkhi(e[4], e[5]);
        up.u[3] = pkhi(e[6], e[7]);
        ph = up.v;
      }
      accL[f] = __builtin_amdgcn_mfma_f32_16x16x32_bf16(ph, ones, accL[f], 0, 0, 0);
      #pragma unroll
      for (int g = 0; g < 4; ++g) {
        acc[f][g] = __builtin_amdgcn_mfma_f32_16x16x32_bf16(ph, bhf[g], acc[f][g], 0, 0, 0);
        acc[f][g] = __builtin_amdgcn_mfma_f32_16x16x32_bf16(ph, blf[g], acc[f][g], 0, 0, 0);
      }
    }
  }

  // merge group-1 partials into group-0 (lane-major LDS, conflict-free)
  const int tid = t & 255;
  if (grp == 1) {
    #pragma unroll
    for (int f = 0; f < 2; ++f) {
      #pragma unroll
      for (int g = 0; g < 4; ++g)
        #pragma unroll
        for (int q = 0; q < 4; ++q)
          ldsm[((f * 4 + g) * 4 + q) * 256 + tid] = acc[f][g][q];
      #pragma unroll
      for (int q = 0; q < 4; ++q)
        ldsm[8192 + (f * 4 + q) * 256 + tid] = accL[f][q];
    }
  }
  __syncthreads();
  if (grp == 0) {
    #pragma unroll
    for (int f = 0; f < 2; ++f) {
      #pragma unroll
      for (int g = 0; g < 4; ++g)
        #pragma unroll
        for (int q = 0; q < 4; ++q)
          acc[f][g][q] += ldsm[((f * 4 + g) * 4 + q) * 256 + tid];
      #pragma unroll
      for (int q = 0; q < 4; ++q)
        accL[f][q] += ldsm[8192 + (f * 4 + q) * 256 + tid];
    }

    #pragma unroll
    for (int f = 0; f < 2; ++f) {
      float linv[4];
      #pragma unroll
      for (int q = 0; q < 4; ++q)
        linv[q] = 1.0f / __shfl(accL[f][q], g4 << 4, 64);
      #pragma unroll
      for (int g = 0; g < 4; ++g)
        #pragma unroll
        for (int q = 0; q < 4; ++q) {
          int row = i0 + f * 16 + g4 * 4 + q;
          int col = g * 16 + l15;
          out[((size_t)bh * CN + row) * CFOUT + col] = acc[f][g][q] * linv[q];
        }
    }
  }
}

extern "C" void kernel_launch(void* const* d_in, const int* in_sizes, int n_in,
                              void* d_out, int out_size, void* d_ws, size_t ws_size,
                              hipStream_t stream) {
  const float* h     = (const float*)d_in[0];
  const int*   adj   = (const int*)d_in[1];
  const float* w     = (const float*)d_in[2];
  const float* a_src = (const float*)d_in[3];
  const float* a_dst = (const float*)d_in[4];
  float* out = (float*)d_out;

  // ws layout (33.5MB, round-6-proven) with temporal aliasing:
  //   [ 0M..16M)  hp f32
  //   [16M..24M)  hh 4M | hl 4M   --after lite-->  hiT 8M (written in mid)
  //   [24M..32M)  loT 8M
  //   [32M..32.5M) vsrc | vdst
  //   [32.5M..33.5M) wh 256K | wl 256K --after lite--> mask 1M (written in mid)
  char* p = (char*)d_ws;
  float* hp  = (float*)p;
  unsigned int* hh = (unsigned int*)(p + (size_t)(16u << 20));
  unsigned int* hl = (unsigned int*)(p + (size_t)(20u << 20));
  short* hiT = (short*)(p + (size_t)(16u << 20));
  short* loT = (short*)(p + (size_t)(24u << 20));
  float* vs  = (float*)(p + (size_t)(32u << 20));
  float* vd  = (float*)(p + (size_t)(32u << 20) + (256u << 10));
  unsigned int* wh = (unsigned int*)(p + (size_t)(32u << 20) + (512u << 10));
  unsigned int* wl = (unsigned int*)(p + (size_t)(32u << 20) + (768u << 10));
  unsigned long long* mask = (unsigned long long*)(p + (size_t)(32u << 20) + (512u << 10));

  hipLaunchKernelGGL(prep, dim3(1032), dim3(256), 0, stream, h, w, hh, hl, wh, wl);
  hipLaunchKernelGGL(hprime_mfma_lite, dim3(512), dim3(256), 0, stream,
                     hh, hl, wh, wl, hp);
  hipLaunchKernelGGL(mid, dim3(1024 + 32768), dim3(256), 0, stream,
                     hp, a_src, a_dst, adj, hiT, loT, vs, vd, mask);
  hipLaunchKernelGGL(gat_attn_mfma, dim3(512), dim3(512), 0, stream,
                     (const unsigned int*)mask, hiT, loT, vs, vd, out);
}

// Round 9
// 90.976 us; speedup vs baseline: 2.5260x; 1.5104x over previous
//
#include <hip/hip_runtime.h>
#include <math.h>

constexpr int CBS   = 8;
constexpr int CN    = 1024;
constexpr int CFIN  = 256;
constexpr int CNH   = 8;
constexpr int CFOUT = 64;

using f32x4 = __attribute__((ext_vector_type(4))) float;
using s16x8 = __attribute__((ext_vector_type(8))) short;

__device__ __forceinline__ short f2bf(float x) {
  __bf16 b = (__bf16)x;
  return __builtin_bit_cast(short, b);
}
__device__ __forceinline__ float bf2f(short s) {
  __bf16 b = __builtin_bit_cast(__bf16, s);
  return (float)b;
}
__device__ __forceinline__ unsigned int pkhi(float a, float b) {
  return (unsigned int)(unsigned short)f2bf(a) |
         ((unsigned int)(unsigned short)f2bf(b) << 16);
}

// ---------------------------------------------------------------------------
// prep [VERIFIED round-7/8]: conv_h (blocks 0..1023) + conv_w (1024..1031)
// ---------------------------------------------------------------------------
__global__ __launch_bounds__(256) void prep(
    const float* __restrict__ h, const float* __restrict__ w,
    unsigned int* __restrict__ hh, unsigned int* __restrict__ hl,
    unsigned int* __restrict__ wh, unsigned int* __restrict__ wl) {
  const int blk = blockIdx.x, t = threadIdx.x;
  if (blk < 1024) {
    size_t i = (size_t)blk * 256 + t;
    const float4* src = (const float4*)(h + i * 8);
    float4 a = src[0], b = src[1];
    float v[8] = {a.x, a.y, a.z, a.w, b.x, b.y, b.z, b.w};
    unsigned int hw[4], lw[4];
    #pragma unroll
    for (int p = 0; p < 4; ++p) {
      float x0 = v[2 * p], x1 = v[2 * p + 1];
      short h0 = f2bf(x0), h1 = f2bf(x1);
      hw[p] = (unsigned int)(unsigned short)h0 | ((unsigned int)(unsigned short)h1 << 16);
      lw[p] = pkhi(x0 - bf2f(h0), x1 - bf2f(h1));
    }
    ((uint4*)hh)[i] = make_uint4(hw[0], hw[1], hw[2], hw[3]);
    ((uint4*)hl)[i] = make_uint4(lw[0], lw[1], lw[2], lw[3]);
  } else {
    const int head = blk - 1024;
    const int o = t & 63, kc = (t >> 6) * 64;
    const float* wg = w + (size_t)head * CFIN * CFOUT;
    unsigned int* dh = wh + ((size_t)head * 64 + o) * 128 + (kc >> 1);
    unsigned int* dl = wl + ((size_t)head * 64 + o) * 128 + (kc >> 1);
    #pragma unroll 4
    for (int k2 = 0; k2 < 32; ++k2) {
      int k = kc + k2 * 2;
      float x0 = wg[(size_t)k * 64 + o], x1 = wg[(size_t)(k + 1) * 64 + o];
      short h0 = f2bf(x0), h1 = f2bf(x1);
      dh[k2] = (unsigned int)(unsigned short)h0 | ((unsigned int)(unsigned short)h1 << 16);
      dl[k2] = pkhi(x0 - bf2f(h0), x1 - bf2f(h1));
    }
  }
}

// ---------------------------------------------------------------------------
// hprime_mfma_lite [VERIFIED round-6/8]: hp = h@w via hi/lo 3-MFMA split.
// ---------------------------------------------------------------------------
__global__ __launch_bounds__(256) void hprime_mfma_lite(
    const unsigned int* __restrict__ hh, const unsigned int* __restrict__ hl,
    const unsigned int* __restrict__ wh, const unsigned int* __restrict__ wl,
    float* __restrict__ hp) {
  const int t = threadIdx.x, lane = t & 63, wid = t >> 6;
  const int bid = blockIdx.x;
  const int blk = (bid & 7) * 64 + (bid >> 3);   // XCD swizzle: one b per XCD
  const int bh = blk >> 3, head = bh & 7, b = bh >> 3;
  const int row0 = (blk & 7) * 128 + wid * 32;
  const int l15 = lane & 15, g4 = lane >> 4;

  const unsigned int* A0 = hh + ((size_t)b * CN + row0 + l15) * 128 + g4 * 4;
  const unsigned int* A1 = hl + ((size_t)b * CN + row0 + l15) * 128 + g4 * 4;
  const unsigned int* B0 = wh + ((size_t)head * 64 + l15) * 128 + g4 * 4;
  const unsigned int* B1 = wl + ((size_t)head * 64 + l15) * 128 + g4 * 4;

  f32x4 acc[2][4];
  #pragma unroll
  for (int f = 0; f < 2; ++f)
    #pragma unroll
    for (int g = 0; g < 4; ++g) acc[f][g] = (f32x4){0.f, 0.f, 0.f, 0.f};

  for (int kw = 0; kw < 128; kw += 16) {   // 32 k per iter
    s16x8 ah[2], al[2], bhf[4], blf[4];
    #pragma unroll
    for (int f = 0; f < 2; ++f) {
      ah[f] = *(const s16x8*)(A0 + (size_t)f * 16 * 128 + kw);
      al[f] = *(const s16x8*)(A1 + (size_t)f * 16 * 128 + kw);
    }
    #pragma unroll
    for (int g = 0; g < 4; ++g) {
      bhf[g] = *(const s16x8*)(B0 + (size_t)g * 16 * 128 + kw);
      blf[g] = *(const s16x8*)(B1 + (size_t)g * 16 * 128 + kw);
    }
    #pragma unroll
    for (int f = 0; f < 2; ++f)
      #pragma unroll
      for (int g = 0; g < 4; ++g) {
        acc[f][g] = __builtin_amdgcn_mfma_f32_16x16x32_bf16(ah[f], bhf[g], acc[f][g], 0, 0, 0);
        acc[f][g] = __builtin_amdgcn_mfma_f32_16x16x32_bf16(ah[f], blf[g], acc[f][g], 0, 0, 0);
        acc[f][g] = __builtin_amdgcn_mfma_f32_16x16x32_bf16(al[f], bhf[g], acc[f][g], 0, 0, 0);
      }
  }

  #pragma unroll
  for (int f = 0; f < 2; ++f)
    #pragma unroll
    for (int g = 0; g < 4; ++g)
      #pragma unroll
      for (int q = 0; q < 4; ++q) {
        int row = row0 + f * 16 + g4 * 4 + q;
        int col = g * 16 + l15;
        hp[((size_t)bh * CN + row) * CFOUT + col] = acc[f][g][q];
      }
}

// ---------------------------------------------------------------------------
// mid (blocks 0..1023): LDS-stage 64x64 hp tile -> (a) FRAGMENT-NATIVE hi/lo
// bf16 blocks fB[bh][jt(32)][g(4)] of 1KB, byte offset = lane*16 matching the
// MFMA B-fragment mapping (lane = g4*16+l15 -> o = g*16+l15, j = jt*32+g4*8+r);
// (b) vsd from the same tile [verified pattern].
// mid (blocks 1024..34815): pack_adj -> TRANSPOSED mask maskT[b][jw32][i].
// ---------------------------------------------------------------------------
__global__ __launch_bounds__(256) void mid(
    const float* __restrict__ hp, const float* __restrict__ a_src,
    const float* __restrict__ a_dst, const int* __restrict__ adj,
    unsigned int* __restrict__ fBh, unsigned int* __restrict__ fBl,
    float* __restrict__ vsrc, float* __restrict__ vdst,
    unsigned int* __restrict__ maskT) {
  __shared__ float s[64 * 65];
  const int blk = blockIdx.x, t = threadIdx.x;
  if (blk >= 1024) {               // pack_adj path (block-uniform branch)
    const int lane = t & 63, w = t >> 6;
    const long long wid = (long long)(blk - 1024) * 4 + w;  // (b*1024+i)*16+jw64
    const int jw = (int)(wid & 15);
    const long long bi = wid >> 4;                          // b*1024 + i
    const int b = (int)(bi >> 10), i = (int)(bi & 1023);
    int a = adj[bi * 1024 + jw * 64 + lane];
    unsigned long long m = __ballot(a > 0);
    if (lane == 0) {
      maskT[((size_t)b * 32 + jw * 2 + 0) * 1024 + i] = (unsigned int)m;
      maskT[((size_t)b * 32 + jw * 2 + 1) * 1024 + i] = (unsigned int)(m >> 32);
    }
    return;
  }
  const int nt = blk & 15, bh = blk >> 4;
  const int n0 = nt * 64;
  const float* src = hp + ((size_t)bh * CN + n0) * CFOUT;
  #pragma unroll
  for (int p = 0; p < 16; ++p) {
    int r = p * 4 + (t >> 6), o = t & 63;
    s[o * 65 + r] = src[(size_t)r * CFOUT + o];
  }
  __syncthreads();
  // fragment-native hi/lo writes: wave = otile g; lane covers (g4,l15)
  {
    const int g = t >> 6;
    const int l = t & 63, l15v = l & 15, g4v = l >> 4;
    const int o = g * 16 + l15v;
    #pragma unroll
    for (int jt = 0; jt < 2; ++jt) {
      float v[8];
      #pragma unroll
      for (int r = 0; r < 8; ++r)
        v[r] = s[o * 65 + jt * 32 + g4v * 8 + r];
      unsigned int hw[4], lw[4];
      #pragma unroll
      for (int p = 0; p < 4; ++p) {
        float x0 = v[2 * p], x1 = v[2 * p + 1];
        short h0 = f2bf(x0), h1 = f2bf(x1);
        hw[p] = (unsigned int)(unsigned short)h0 | ((unsigned int)(unsigned short)h1 << 16);
        lw[p] = pkhi(x0 - bf2f(h0), x1 - bf2f(h1));
      }
      size_t base = (((size_t)bh * 32 + nt * 2 + jt) * 4 + g) * 256 + (size_t)l * 4;
      *(uint4*)(fBh + base) = make_uint4(hw[0], hw[1], hw[2], hw[3]);
      *(uint4*)(fBl + base) = make_uint4(lw[0], lw[1], lw[2], lw[3]);
    }
  }
  // vsd from the same LDS tile [verified]
  {
    const int lane = t & 63, wid = t >> 6;
    const int head = bh & 7;
    const float asv = a_src[head * CFOUT + lane];
    const float adv = a_dst[head * CFOUT + lane];
    #pragma unroll
    for (int q = 0; q < 16; ++q) {
      int r = wid * 16 + q;
      float v = s[lane * 65 + r];
      float tv = tanhf(v);
      float vsx = tv * asv, vdx = tv * adv;
      for (int mm = 32; mm; mm >>= 1) {
        vsx += __shfl_xor(vsx, mm, 64);
        vdx += __shfl_xor(vdx, mm, 64);
      }
      if (lane == 0) {
        vsrc[(size_t)bh * CN + n0 + r] = vsx;
        vdst[(size_t)bh * CN + n0 + r] = vdx;
      }
    }
  }
}

// ---------------------------------------------------------------------------
// attn [round-8 verified structure; B + mask loads now CONTIGUOUS]:
// 512 blocks x 512 thr (8 waves). grp 0: j in [0,512); grp 1: [512,1024).
// B fragments from fB (1KB/wave contiguous); mask from maskT (64B contiguous).
// ---------------------------------------------------------------------------
__global__ __launch_bounds__(512) void gat_attn_mfma(
    const unsigned int* __restrict__ maskT,
    const unsigned int* __restrict__ fBh, const unsigned int* __restrict__ fBl,
    const float* __restrict__ vsrc, const float* __restrict__ vdst,
    float* __restrict__ out) {
  __shared__ float ldsm[32 * 256 + 8 * 256];   // 40KB partial merge
  const int t = threadIdx.x, lane = t & 63, wid = t >> 6;
  const int w4 = wid & 3, grp = wid >> 2;
  const int bid = blockIdx.x;
  const int blk = (bid & 7) * 64 + (bid >> 3);   // XCD swizzle: 8 bh per XCD
  const int bh = blk >> 3, b = bh >> 3;
  const int i0 = (blk & 7) * 128 + w4 * 32;
  const int l15 = lane & 15, g4 = lane >> 4;
  const float LOG2E = 1.44269504088896340736f;

  const float* dstp = vdst + (size_t)bh * CN;

  float M = -INFINITY;
  #pragma unroll
  for (int s_ = 0; s_ < 16; ++s_) M = fmaxf(M, dstp[s_ * 64 + lane]);
  #pragma unroll
  for (int mm = 32; mm; mm >>= 1) M = fmaxf(M, __shfl_xor(M, mm, 64));

  float sA[2], sB[2];
  #pragma unroll
  for (int f = 0; f < 2; ++f) {
    float sv = vsrc[(size_t)bh * CN + i0 + f * 16 + l15];
    float c = sv + M;
    c = fmaxf(c, 0.2f * c);            // C_i = LR(src_i + M) >= row max
    float cK = c * LOG2E;
    sA[f] = sv * LOG2E - cK;
    sB[f] = 0.2f * (sv * LOG2E) - cK;
  }

  f32x4 acc[2][4], accL[2];
  #pragma unroll
  for (int f = 0; f < 2; ++f) {
    accL[f] = (f32x4){0.f, 0.f, 0.f, 0.f};
    #pragma unroll
    for (int g = 0; g < 4; ++g) acc[f][g] = (f32x4){0.f, 0.f, 0.f, 0.f};
  }

  s16x8 ones;
  {
    union { s16x8 v; unsigned int u[4]; } uo;
    unsigned int ow = (l15 == 0) ? 0x3F803F80u : 0u;
    uo.u[0] = uo.u[1] = uo.u[2] = uo.u[3] = ow;
    ones = uo.v;
  }

  // fragment bases: 128 fragment-blocks per bh (32 jt x 4 g), 64 s16x8 each
  const s16x8* FH = (const s16x8*)fBh + (size_t)bh * 128 * 64;
  const s16x8* FL = (const s16x8*)fBl + (size_t)bh * 128 * 64;
  const unsigned int* mT = maskT + (size_t)b * 32 * 1024;
  const float K02 = 0.2f * LOG2E;
  const int jbase = grp * 512;

  for (int j0 = jbase; j0 < jbase + 512; j0 += 32) {
    const float* dj = dstp + j0 + g4 * 8;
    float4 d0 = *(const float4*)&dj[0];
    float4 d1 = *(const float4*)&dj[4];
    float dK[8], dK2[8];
    dK[0] = d0.x * LOG2E; dK[1] = d0.y * LOG2E; dK[2] = d0.z * LOG2E; dK[3] = d0.w * LOG2E;
    dK[4] = d1.x * LOG2E; dK[5] = d1.y * LOG2E; dK[6] = d1.z * LOG2E; dK[7] = d1.w * LOG2E;
    dK2[0] = d0.x * K02; dK2[1] = d0.y * K02; dK2[2] = d0.z * K02; dK2[3] = d0.w * K02;
    dK2[4] = d1.x * K02; dK2[5] = d1.y * K02; dK2[6] = d1.z * K02; dK2[7] = d1.w * K02;

    const int fb0 = (j0 >> 5) * 4;
    s16x8 bhf[4], blf[4];
    #pragma unroll
    for (int g = 0; g < 4; ++g) {
      bhf[g] = FH[(size_t)(fb0 + g) * 64 + lane];
      blf[g] = FL[(size_t)(fb0 + g) * 64 + lane];
    }

    #pragma unroll
    for (int f = 0; f < 2; ++f) {
      unsigned int word = mT[(size_t)(j0 >> 5) * 1024 + i0 + f * 16 + l15];
      unsigned int byte = (word >> (g4 * 8)) & 0xFFu;
      float e[8];
      #pragma unroll
      for (int r = 0; r < 8; ++r) {
        float lr = fmaxf(sA[f] + dK[r], sB[f] + dK2[r]);
        lr = (byte & (1u << r)) ? lr : -500.f;
        e[r] = __builtin_amdgcn_exp2f(lr);
      }
      s16x8 ph;
      {
        union { s16x8 v; unsigned int u[4]; } up;
        up.u[0] = pkhi(e[0], e[1]);
        up.u[1] = pkhi(e[2], e[3]);
        up.u[2] = pkhi(e[4], e[5]);
        up.u[3] = pkhi(e[6], e[7]);
        ph = up.v;
      }
      accL[f] = __builtin_amdgcn_mfma_f32_16x16x32_bf16(ph, ones, accL[f], 0, 0, 0);
      #pragma unroll
      for (int g = 0; g < 4; ++g) {
        acc[f][g] = __builtin_amdgcn_mfma_f32_16x16x32_bf16(ph, bhf[g], acc[f][g], 0, 0, 0);
        acc[f][g] = __builtin_amdgcn_mfma_f32_16x16x32_bf16(ph, blf[g], acc[f][g], 0, 0, 0);
      }
    }
  }

  // merge group-1 partials into group-0 (lane-major LDS, conflict-free)
  const int tid = t & 255;
  if (grp == 1) {
    #pragma unroll
    for (int f = 0; f < 2; ++f) {
      #pragma unroll
      for (int g = 0; g < 4; ++g)
        #pragma unroll
        for (int q = 0; q < 4; ++q)
          ldsm[((f * 4 + g) * 4 + q) * 256 + tid] = acc[f][g][q];
      #pragma unroll
      for (int q = 0; q < 4; ++q)
        ldsm[8192 + (f * 4 + q) * 256 + tid] = accL[f][q];
    }
  }
  __syncthreads();
  if (grp == 0) {
    #pragma unroll
    for (int f = 0; f < 2; ++f) {
      #pragma unroll
      for (int g = 0; g < 4; ++g)
        #pragma unroll
        for (int q = 0; q < 4; ++q)
          acc[f][g][q] += ldsm[((f * 4 + g) * 4 + q) * 256 + tid];
      #pragma unroll
      for (int q = 0; q < 4; ++q)
        accL[f][q] += ldsm[8192 + (f * 4 + q) * 256 + tid];
    }

    #pragma unroll
    for (int f = 0; f < 2; ++f) {
      float linv[4];
      #pragma unroll
      for (int q = 0; q < 4; ++q)
        linv[q] = 1.0f / __shfl(accL[f][q], g4 << 4, 64);
      #pragma unroll
      for (int g = 0; g < 4; ++g)
        #pragma unroll
        for (int q = 0; q < 4; ++q) {
          int row = i0 + f * 16 + g4 * 4 + q;
          int col = g * 16 + l15;
          out[((size_t)bh * CN + row) * CFOUT + col] = acc[f][g][q] * linv[q];
        }
    }
  }
}

extern "C" void kernel_launch(void* const* d_in, const int* in_sizes, int n_in,
                              void* d_out, int out_size, void* d_ws, size_t ws_size,
                              hipStream_t stream) {
  const float* h     = (const float*)d_in[0];
  const int*   adj   = (const int*)d_in[1];
  const float* w     = (const float*)d_in[2];
  const float* a_src = (const float*)d_in[3];
  const float* a_dst = (const float*)d_in[4];
  float* out = (float*)d_out;

  // ws layout (33.5MB, round-6/8-proven footprint) with temporal aliasing:
  //   [ 0M..16M)  hp f32
  //   [16M..24M)  hh 4M | hl 4M   --after lite-->  fBh 8M (written in mid)
  //   [24M..32M)  fBl 8M
  //   [32M..32.5M) vsrc | vdst
  //   [32.5M..33.5M) wh 256K | wl 256K --after lite--> maskT 1M (written in mid)
  char* p = (char*)d_ws;
  float* hp  = (float*)p;
  unsigned int* hh = (unsigned int*)(p + (size_t)(16u << 20));
  unsigned int* hl = (unsigned int*)(p + (size_t)(20u << 20));
  unsigned int* fBh = (unsigned int*)(p + (size_t)(16u << 20));
  unsigned int* fBl = (unsigned int*)(p + (size_t)(24u << 20));
  float* vs  = (float*)(p + (size_t)(32u << 20));
  float* vd  = (float*)(p + (size_t)(32u << 20) + (256u << 10));
  unsigned int* wh = (unsigned int*)(p + (size_t)(32u << 20) + (512u << 10));
  unsigned int* wl = (unsigned int*)(p + (size_t)(32u << 20) + (768u << 10));
  unsigned int* maskT = (unsigned int*)(p + (size_t)(32u << 20) + (512u << 10));

  hipLaunchKernelGGL(prep, dim3(1032), dim3(256), 0, stream, h, w, hh, hl, wh, wl);
  hipLaunchKernelGGL(hprime_mfma_lite, dim3(512), dim3(256), 0, stream,
                     hh, hl, wh, wl, hp);
  hipLaunchKernelGGL(mid, dim3(1024 + 32768), dim3(256), 0, stream,
                     hp, a_src, a_dst, adj, fBh, fBl, vs, vd, maskT);
  hipLaunchKernelGGL(gat_attn_mfma, dim3(512), dim3(512), 0, stream,
                     maskT, fBh, fBl, vs, vd, out);
}

// Round 10
// 89.261 us; speedup vs baseline: 2.5745x; 1.0192x over previous
//
#include <hip/hip_runtime.h>
#include <math.h>

constexpr int CBS   = 8;
constexpr int CN    = 1024;
constexpr int CFIN  = 256;
constexpr int CNH   = 8;
constexpr int CFOUT = 64;

using f32x4 = __attribute__((ext_vector_type(4))) float;
using s16x8 = __attribute__((ext_vector_type(8))) short;

__device__ __forceinline__ short f2bf(float x) {
  __bf16 b = (__bf16)x;
  return __builtin_bit_cast(short, b);
}
__device__ __forceinline__ float bf2f(short s) {
  __bf16 b = __builtin_bit_cast(__bf16, s);
  return (float)b;
}
__device__ __forceinline__ unsigned int pkhi(float a, float b) {
  return (unsigned int)(unsigned short)f2bf(a) |
         ((unsigned int)(unsigned short)f2bf(b) << 16);
}

// ---------------------------------------------------------------------------
// prep [VERIFIED round-7/8/9]: conv_h (blocks 0..1023) + conv_w (1024..1031)
// ---------------------------------------------------------------------------
__global__ __launch_bounds__(256) void prep(
    const float* __restrict__ h, const float* __restrict__ w,
    unsigned int* __restrict__ hh, unsigned int* __restrict__ hl,
    unsigned int* __restrict__ wh, unsigned int* __restrict__ wl) {
  const int blk = blockIdx.x, t = threadIdx.x;
  if (blk < 1024) {
    size_t i = (size_t)blk * 256 + t;
    const float4* src = (const float4*)(h + i * 8);
    float4 a = src[0], b = src[1];
    float v[8] = {a.x, a.y, a.z, a.w, b.x, b.y, b.z, b.w};
    unsigned int hw[4], lw[4];
    #pragma unroll
    for (int p = 0; p < 4; ++p) {
      float x0 = v[2 * p], x1 = v[2 * p + 1];
      short h0 = f2bf(x0), h1 = f2bf(x1);
      hw[p] = (unsigned int)(unsigned short)h0 | ((unsigned int)(unsigned short)h1 << 16);
      lw[p] = pkhi(x0 - bf2f(h0), x1 - bf2f(h1));
    }
    ((uint4*)hh)[i] = make_uint4(hw[0], hw[1], hw[2], hw[3]);
    ((uint4*)hl)[i] = make_uint4(lw[0], lw[1], lw[2], lw[3]);
  } else {
    const int head = blk - 1024;
    const int o = t & 63, kc = (t >> 6) * 64;
    const float* wg = w + (size_t)head * CFIN * CFOUT;
    unsigned int* dh = wh + ((size_t)head * 64 + o) * 128 + (kc >> 1);
    unsigned int* dl = wl + ((size_t)head * 64 + o) * 128 + (kc >> 1);
    #pragma unroll 4
    for (int k2 = 0; k2 < 32; ++k2) {
      int k = kc + k2 * 2;
      float x0 = wg[(size_t)k * 64 + o], x1 = wg[(size_t)(k + 1) * 64 + o];
      short h0 = f2bf(x0), h1 = f2bf(x1);
      dh[k2] = (unsigned int)(unsigned short)h0 | ((unsigned int)(unsigned short)h1 << 16);
      dl[k2] = pkhi(x0 - bf2f(h0), x1 - bf2f(h1));
    }
  }
}

// ---------------------------------------------------------------------------
// liteF (blocks 0..511): hp = h@w via hi/lo 3-MFMA split [VERIFIED core];
// epilogue (NEW, per-wave LDS tile, no syncthreads):
//   - vsrc/vdst from acc (round-4 vsd reduce logic, layout re-derived)
//   - fragment-native fB hi/lo writes, byte-identical to round-9 mid's writer:
//     fB[bh][JT][g] lane l elem r  =  hp[JT*32 + (l>>4)*8 + r][g*16 + (l&15)]
//     where each wave's 32 rows are exactly one JT.
// liteF (blocks 512..33279): packT [VERIFIED round-9] -> maskT[b][jw32][i].
// ---------------------------------------------------------------------------
__global__ __launch_bounds__(256) void liteF(
    const unsigned int* __restrict__ hh, const unsigned int* __restrict__ hl,
    const unsigned int* __restrict__ wh, const unsigned int* __restrict__ wl,
    const float* __restrict__ a_src, const float* __restrict__ a_dst,
    const int* __restrict__ adj,
    unsigned int* __restrict__ fBh, unsigned int* __restrict__ fBl,
    float* __restrict__ vsrc, float* __restrict__ vdst,
    unsigned int* __restrict__ maskT) {
  __shared__ float tileT[4][64 * 33];   // per-wave [o][n_local], pad 33
  const int bid = blockIdx.x, t = threadIdx.x;
  if (bid >= 512) {                     // packT path [verified round-9]
    const int lane = t & 63, w = t >> 6;
    const long long wid = (long long)(bid - 512) * 4 + w;   // (b*1024+i)*16+jw64
    const int jw = (int)(wid & 15);
    const long long bi = wid >> 4;                          // b*1024 + i
    const int b = (int)(bi >> 10), i = (int)(bi & 1023);
    int a = adj[bi * 1024 + jw * 64 + lane];
    unsigned long long m = __ballot(a > 0);
    if (lane == 0) {
      maskT[((size_t)b * 32 + jw * 2 + 0) * 1024 + i] = (unsigned int)m;
      maskT[((size_t)b * 32 + jw * 2 + 1) * 1024 + i] = (unsigned int)(m >> 32);
    }
    return;
  }
  const int lane = t & 63, wid = t >> 6;
  const int blk = (bid & 7) * 64 + (bid >> 3);   // XCD swizzle: one b per XCD
  const int bh = blk >> 3, head = bh & 7, b = bh >> 3;
  const int row0 = (blk & 7) * 128 + wid * 32;
  const int l15 = lane & 15, g4 = lane >> 4;

  const unsigned int* A0 = hh + ((size_t)b * CN + row0 + l15) * 128 + g4 * 4;
  const unsigned int* A1 = hl + ((size_t)b * CN + row0 + l15) * 128 + g4 * 4;
  const unsigned int* B0 = wh + ((size_t)head * 64 + l15) * 128 + g4 * 4;
  const unsigned int* B1 = wl + ((size_t)head * 64 + l15) * 128 + g4 * 4;

  f32x4 acc[2][4];
  #pragma unroll
  for (int f = 0; f < 2; ++f)
    #pragma unroll
    for (int g = 0; g < 4; ++g) acc[f][g] = (f32x4){0.f, 0.f, 0.f, 0.f};

  for (int kw = 0; kw < 128; kw += 16) {   // 32 k per iter
    s16x8 ah[2], al[2], bhf[4], blf[4];
    #pragma unroll
    for (int f = 0; f < 2; ++f) {
      ah[f] = *(const s16x8*)(A0 + (size_t)f * 16 * 128 + kw);
      al[f] = *(const s16x8*)(A1 + (size_t)f * 16 * 128 + kw);
    }
    #pragma unroll
    for (int g = 0; g < 4; ++g) {
      bhf[g] = *(const s16x8*)(B0 + (size_t)g * 16 * 128 + kw);
      blf[g] = *(const s16x8*)(B1 + (size_t)g * 16 * 128 + kw);
    }
    #pragma unroll
    for (int f = 0; f < 2; ++f)
      #pragma unroll
      for (int g = 0; g < 4; ++g) {
        acc[f][g] = __builtin_amdgcn_mfma_f32_16x16x32_bf16(ah[f], bhf[g], acc[f][g], 0, 0, 0);
        acc[f][g] = __builtin_amdgcn_mfma_f32_16x16x32_bf16(ah[f], blf[g], acc[f][g], 0, 0, 0);
        acc[f][g] = __builtin_amdgcn_mfma_f32_16x16x32_bf16(al[f], bhf[g], acc[f][g], 0, 0, 0);
      }
  }

  // --- vsrc/vdst from acc (reduce over o; lane holds col g*16+l15) ---
  {
    float as4[4], ad4[4];
    #pragma unroll
    for (int g = 0; g < 4; ++g) {
      as4[g] = a_src[head * CFOUT + g * 16 + l15];
      ad4[g] = a_dst[head * CFOUT + g * 16 + l15];
    }
    #pragma unroll
    for (int f = 0; f < 2; ++f) {
      float ps[4] = {0.f, 0.f, 0.f, 0.f}, pd[4] = {0.f, 0.f, 0.f, 0.f};
      #pragma unroll
      for (int g = 0; g < 4; ++g)
        #pragma unroll
        for (int q = 0; q < 4; ++q) {
          float tv = tanhf(acc[f][g][q]);
          ps[q] += tv * as4[g];
          pd[q] += tv * ad4[g];
        }
      #pragma unroll
      for (int q = 0; q < 4; ++q) {
        #pragma unroll
        for (int mm = 1; mm < 16; mm <<= 1) {
          ps[q] += __shfl_xor(ps[q], mm, 64);
          pd[q] += __shfl_xor(pd[q], mm, 64);
        }
      }
      if (l15 == 0) {
        #pragma unroll
        for (int q = 0; q < 4; ++q) {
          int row = row0 + f * 16 + g4 * 4 + q;
          vsrc[(size_t)bh * CN + row] = ps[q];
          vdst[(size_t)bh * CN + row] = pd[q];
        }
      }
    }
  }

  // --- fragment-native fB split via per-wave LDS tile ---
  {
    float* tw = tileT[wid];
    // write C-layout: row n_local = f*16+g4*4+q, col o = g*16+l15
    #pragma unroll
    for (int f = 0; f < 2; ++f)
      #pragma unroll
      for (int g = 0; g < 4; ++g)
        #pragma unroll
        for (int q = 0; q < 4; ++q)
          tw[(g * 16 + l15) * 33 + f * 16 + g4 * 4 + q] = acc[f][g][q];
    // read B-fragment layout: this lane needs rows g4*8+r, col g*16+l15
    const int JT = (blk & 7) * 4 + wid;    // global j-tile = row0/32
    #pragma unroll
    for (int g = 0; g < 4; ++g) {
      float v[8];
      #pragma unroll
      for (int r = 0; r < 8; ++r)
        v[r] = tw[(g * 16 + l15) * 33 + g4 * 8 + r];
      unsigned int hw[4], lw[4];
      #pragma unroll
      for (int p = 0; p < 4; ++p) {
        float x0 = v[2 * p], x1 = v[2 * p + 1];
        short h0 = f2bf(x0), h1 = f2bf(x1);
        hw[p] = (unsigned int)(unsigned short)h0 | ((unsigned int)(unsigned short)h1 << 16);
        lw[p] = pkhi(x0 - bf2f(h0), x1 - bf2f(h1));
      }
      size_t base = (((size_t)bh * 32 + JT) * 4 + g) * 256 + (size_t)lane * 4;
      *(uint4*)(fBh + base) = make_uint4(hw[0], hw[1], hw[2], hw[3]);
      *(uint4*)(fBl + base) = make_uint4(lw[0], lw[1], lw[2], lw[3]);
    }
  }
}

// ---------------------------------------------------------------------------
// attn [VERIFIED round-9 structure; dK2 folded into fmaf]:
// 512 blocks x 512 thr (8 waves). grp 0: j in [0,512); grp 1: [512,1024).
// B fragments from fB (1KB/wave contiguous); mask from maskT (64B contiguous).
// ---------------------------------------------------------------------------
__global__ __launch_bounds__(512) void gat_attn_mfma(
    const unsigned int* __restrict__ maskT,
    const unsigned int* __restrict__ fBh, const unsigned int* __restrict__ fBl,
    const float* __restrict__ vsrc, const float* __restrict__ vdst,
    float* __restrict__ out) {
  __shared__ float ldsm[32 * 256 + 8 * 256];   // 40KB partial merge
  const int t = threadIdx.x, lane = t & 63, wid = t >> 6;
  const int w4 = wid & 3, grp = wid >> 2;
  const int bid = blockIdx.x;
  const int blk = (bid & 7) * 64 + (bid >> 3);   // XCD swizzle: 8 bh per XCD
  const int bh = blk >> 3, b = bh >> 3;
  const int i0 = (blk & 7) * 128 + w4 * 32;
  const int l15 = lane & 15, g4 = lane >> 4;
  const float LOG2E = 1.44269504088896340736f;

  const float* dstp = vdst + (size_t)bh * CN;

  float M = -INFINITY;
  #pragma unroll
  for (int s_ = 0; s_ < 16; ++s_) M = fmaxf(M, dstp[s_ * 64 + lane]);
  #pragma unroll
  for (int mm = 32; mm; mm >>= 1) M = fmaxf(M, __shfl_xor(M, mm, 64));

  float sA[2], sB[2];
  #pragma unroll
  for (int f = 0; f < 2; ++f) {
    float sv = vsrc[(size_t)bh * CN + i0 + f * 16 + l15];
    float c = sv + M;
    c = fmaxf(c, 0.2f * c);            // C_i = LR(src_i + M) >= row max
    float cK = c * LOG2E;
    sA[f] = sv * LOG2E - cK;
    sB[f] = 0.2f * (sv * LOG2E) - cK;
  }

  f32x4 acc[2][4], accL[2];
  #pragma unroll
  for (int f = 0; f < 2; ++f) {
    accL[f] = (f32x4){0.f, 0.f, 0.f, 0.f};
    #pragma unroll
    for (int g = 0; g < 4; ++g) acc[f][g] = (f32x4){0.f, 0.f, 0.f, 0.f};
  }

  s16x8 ones;
  {
    union { s16x8 v; unsigned int u[4]; } uo;
    unsigned int ow = (l15 == 0) ? 0x3F803F80u : 0u;
    uo.u[0] = uo.u[1] = uo.u[2] = uo.u[3] = ow;
    ones = uo.v;
  }

  const s16x8* FH = (const s16x8*)fBh + (size_t)bh * 128 * 64;
  const s16x8* FL = (const s16x8*)fBl + (size_t)bh * 128 * 64;
  const unsigned int* mT = maskT + (size_t)b * 32 * 1024;
  const int jbase = grp * 512;

  for (int j0 = jbase; j0 < jbase + 512; j0 += 32) {
    const float* dj = dstp + j0 + g4 * 8;
    float4 d0 = *(const float4*)&dj[0];
    float4 d1 = *(const float4*)&dj[4];
    float dK[8];
    dK[0] = d0.x * LOG2E; dK[1] = d0.y * LOG2E; dK[2] = d0.z * LOG2E; dK[3] = d0.w * LOG2E;
    dK[4] = d1.x * LOG2E; dK[5] = d1.y * LOG2E; dK[6] = d1.z * LOG2E; dK[7] = d1.w * LOG2E;

    const int fb0 = (j0 >> 5) * 4;
    s16x8 bhf[4], blf[4];
    #pragma unroll
    for (int g = 0; g < 4; ++g) {
      bhf[g] = FH[(size_t)(fb0 + g) * 64 + lane];
      blf[g] = FL[(size_t)(fb0 + g) * 64 + lane];
    }

    #pragma unroll
    for (int f = 0; f < 2; ++f) {
      unsigned int word = mT[(size_t)(j0 >> 5) * 1024 + i0 + f * 16 + l15];
      unsigned int byte = (word >> (g4 * 8)) & 0xFFu;
      float e[8];
      #pragma unroll
      for (int r = 0; r < 8; ++r) {
        float lr = fmaxf(sA[f] + dK[r], fmaf(0.2f, dK[r], sB[f]));
        lr = (byte & (1u << r)) ? lr : -500.f;
        e[r] = __builtin_amdgcn_exp2f(lr);
      }
      s16x8 ph;
      {
        union { s16x8 v; unsigned int u[4]; } up;
        up.u[0] = pkhi(e[0], e[1]);
        up.u[1] = pkhi(e[2], e[3]);
        up.u[2] = pkhi(e[4], e[5]);
        up.u[3] = pkhi(e[6], e[7]);
        ph = up.v;
      }
      accL[f] = __builtin_amdgcn_mfma_f32_16x16x32_bf16(ph, ones, accL[f], 0, 0, 0);
      #pragma unroll
      for (int g = 0; g < 4; ++g) {
        acc[f][g] = __builtin_amdgcn_mfma_f32_16x16x32_bf16(ph, bhf[g], acc[f][g], 0, 0, 0);
        acc[f][g] = __builtin_amdgcn_mfma_f32_16x16x32_bf16(ph, blf[g], acc[f][g], 0, 0, 0);
      }
    }
  }

  // merge group-1 partials into group-0 (lane-major LDS, conflict-free)
  const int tid = t & 255;
  if (grp == 1) {
    #pragma unroll
    for (int f = 0; f < 2; ++f) {
      #pragma unroll
      for (int g = 0; g < 4; ++g)
        #pragma unroll
        for (int q = 0; q < 4; ++q)
          ldsm[((f * 4 + g) * 4 + q) * 256 + tid] = acc[f][g][q];
      #pragma unroll
      for (int q = 0; q < 4; ++q)
        ldsm[8192 + (f * 4 + q) * 256 + tid] = accL[f][q];
    }
  }
  __syncthreads();
  if (grp == 0) {
    #pragma unroll
    for (int f = 0; f < 2; ++f) {
      #pragma unroll
      for (int g = 0; g < 4; ++g)
        #pragma unroll
        for (int q = 0; q < 4; ++q)
          acc[f][g][q] += ldsm[((f * 4 + g) * 4 + q) * 256 + tid];
      #pragma unroll
      for (int q = 0; q < 4; ++q)
        accL[f][q] += ldsm[8192 + (f * 4 + q) * 256 + tid];
    }

    #pragma unroll
    for (int f = 0; f < 2; ++f) {
      float linv[4];
      #pragma unroll
      for (int q = 0; q < 4; ++q)
        linv[q] = 1.0f / __shfl(accL[f][q], g4 << 4, 64);
      #pragma unroll
      for (int g = 0; g < 4; ++g)
        #pragma unroll
        for (int q = 0; q < 4; ++q) {
          int row = i0 + f * 16 + g4 * 4 + q;
          int col = g * 16 + l15;
          out[((size_t)bh * CN + row) * CFOUT + col] = acc[f][g][q] * linv[q];
        }
    }
  }
}

extern "C" void kernel_launch(void* const* d_in, const int* in_sizes, int n_in,
                              void* d_out, int out_size, void* d_ws, size_t ws_size,
                              hipStream_t stream) {
  const float* h     = (const float*)d_in[0];
  const int*   adj   = (const int*)d_in[1];
  const float* w     = (const float*)d_in[2];
  const float* a_src = (const float*)d_in[3];
  const float* a_dst = (const float*)d_in[4];
  float* out = (float*)d_out;

  // ws layout (26MB, no aliasing — hp eliminated):
  //   [ 0M.. 4M) hh   [ 4M.. 8M) hl
  //   [ 8M..16M) fBh  [16M..24M) fBl
  //   [24M..24.5M) wh|wl  [24.5M..25M) vsrc|vdst  [25M..26M) maskT
  char* p = (char*)d_ws;
  unsigned int* hh  = (unsigned int*)p;
  unsigned int* hl  = (unsigned int*)(p + (size_t)(4u << 20));
  unsigned int* fBh = (unsigned int*)(p + (size_t)(8u << 20));
  unsigned int* fBl = (unsigned int*)(p + (size_t)(16u << 20));
  unsigned int* wh  = (unsigned int*)(p + (size_t)(24u << 20));
  unsigned int* wl  = (unsigned int*)(p + (size_t)(24u << 20) + (256u << 10));
  float* vs  = (float*)(p + (size_t)(24u << 20) + (512u << 10));
  float* vd  = (float*)(p + (size_t)(24u << 20) + (768u << 10));
  unsigned int* maskT = (unsigned int*)(p + (size_t)(25u << 20));

  hipLaunchKernelGGL(prep, dim3(1032), dim3(256), 0, stream, h, w, hh, hl, wh, wl);
  hipLaunchKernelGGL(liteF, dim3(512 + 32768), dim3(256), 0, stream,
                     hh, hl, wh, wl, a_src, a_dst, adj, fBh, fBl, vs, vd, maskT);
  hipLaunchKernelGGL(gat_attn_mfma, dim3(512), dim3(512), 0, stream,
                     maskT, fBh, fBl, vs, vd, out);
}

// Round 11
// 79.994 us; speedup vs baseline: 2.8728x; 1.1159x over previous
//
#include <hip/hip_runtime.h>
#include <math.h>

constexpr int CBS   = 8;
constexpr int CN    = 1024;
constexpr int CFIN  = 256;
constexpr int CNH   = 8;
constexpr int CFOUT = 64;

using f32x4 = __attribute__((ext_vector_type(4))) float;
using s16x8 = __attribute__((ext_vector_type(8))) short;

__device__ __forceinline__ short f2bf(float x) {
  __bf16 b = (__bf16)x;
  return __builtin_bit_cast(short, b);
}
__device__ __forceinline__ float bf2f(short s) {
  __bf16 b = __builtin_bit_cast(__bf16, s);
  return (float)b;
}
__device__ __forceinline__ unsigned int pkhi(float a, float b) {
  return (unsigned int)(unsigned short)f2bf(a) |
         ((unsigned int)(unsigned short)f2bf(b) << 16);
}

// ---------------------------------------------------------------------------
// prep: conv_h [verified] (blocks 0..1023) + conv_w [verified] (1024..1031)
//     + packT [verified logic, FAT WAVES] (blocks 1032..3079):
//       one wave packs one (b,i) row: 16 batched 256B loads -> 16 ballots.
//       No LDS in this kernel -> full occupancy for the latency-bound path.
// ---------------------------------------------------------------------------
__global__ __launch_bounds__(256) void prep(
    const float* __restrict__ h, const float* __restrict__ w,
    const int* __restrict__ adj,
    unsigned int* __restrict__ hh, unsigned int* __restrict__ hl,
    unsigned int* __restrict__ wh, unsigned int* __restrict__ wl,
    unsigned int* __restrict__ maskT) {
  const int blk = blockIdx.x, t = threadIdx.x;
  if (blk < 1024) {
    size_t i = (size_t)blk * 256 + t;
    const float4* src = (const float4*)(h + i * 8);
    float4 a = src[0], b = src[1];
    float v[8] = {a.x, a.y, a.z, a.w, b.x, b.y, b.z, b.w};
    unsigned int hw[4], lw[4];
    #pragma unroll
    for (int p = 0; p < 4; ++p) {
      float x0 = v[2 * p], x1 = v[2 * p + 1];
      short h0 = f2bf(x0), h1 = f2bf(x1);
      hw[p] = (unsigned int)(unsigned short)h0 | ((unsigned int)(unsigned short)h1 << 16);
      lw[p] = pkhi(x0 - bf2f(h0), x1 - bf2f(h1));
    }
    ((uint4*)hh)[i] = make_uint4(hw[0], hw[1], hw[2], hw[3]);
    ((uint4*)hl)[i] = make_uint4(lw[0], lw[1], lw[2], lw[3]);
  } else if (blk < 1032) {
    const int head = blk - 1024;
    const int o = t & 63, kc = (t >> 6) * 64;
    const float* wg = w + (size_t)head * CFIN * CFOUT;
    unsigned int* dh = wh + ((size_t)head * 64 + o) * 128 + (kc >> 1);
    unsigned int* dl = wl + ((size_t)head * 64 + o) * 128 + (kc >> 1);
    #pragma unroll 4
    for (int k2 = 0; k2 < 32; ++k2) {
      int k = kc + k2 * 2;
      float x0 = wg[(size_t)k * 64 + o], x1 = wg[(size_t)(k + 1) * 64 + o];
      short h0 = f2bf(x0), h1 = f2bf(x1);
      dh[k2] = (unsigned int)(unsigned short)h0 | ((unsigned int)(unsigned short)h1 << 16);
      dl[k2] = pkhi(x0 - bf2f(h0), x1 - bf2f(h1));
    }
  } else {
    const int lane = t & 63, wv = t >> 6;
    const long long bi = (long long)(blk - 1032) * 4 + wv;   // b*1024 + i
    const int b = (int)(bi >> 10), i = (int)(bi & 1023);
    const int* ap = adj + bi * 1024 + lane;
    int a[16];
    #pragma unroll
    for (int jw = 0; jw < 16; ++jw) a[jw] = ap[jw * 64];     // 16 loads in flight
    #pragma unroll
    for (int jw = 0; jw < 16; ++jw) {
      unsigned long long m = __ballot(a[jw] > 0);
      if (lane == 0) {
        maskT[((size_t)b * 32 + jw * 2 + 0) * 1024 + i] = (unsigned int)m;
        maskT[((size_t)b * 32 + jw * 2 + 1) * 1024 + i] = (unsigned int)(m >> 32);
      }
    }
  }
}

// ---------------------------------------------------------------------------
// liteF [VERIFIED round-10 GEMM core + epilogue; pack branch removed]:
// 512 blocks. hp = h@w via hi/lo 3-MFMA split; epilogue writes vsrc/vdst and
// fragment-native fB hi/lo (per-wave LDS tile, no syncthreads).
// ---------------------------------------------------------------------------
__global__ __launch_bounds__(256) void liteF(
    const unsigned int* __restrict__ hh, const unsigned int* __restrict__ hl,
    const unsigned int* __restrict__ wh, const unsigned int* __restrict__ wl,
    const float* __restrict__ a_src, const float* __restrict__ a_dst,
    unsigned int* __restrict__ fBh, unsigned int* __restrict__ fBl,
    float* __restrict__ vsrc, float* __restrict__ vdst) {
  __shared__ float tileT[4][64 * 33];   // per-wave [o][n_local], pad 33
  const int bid = blockIdx.x, t = threadIdx.x;
  const int lane = t & 63, wid = t >> 6;
  const int blk = (bid & 7) * 64 + (bid >> 3);   // XCD swizzle: one b per XCD
  const int bh = blk >> 3, head = bh & 7, b = bh >> 3;
  const int row0 = (blk & 7) * 128 + wid * 32;
  const int l15 = lane & 15, g4 = lane >> 4;

  const unsigned int* A0 = hh + ((size_t)b * CN + row0 + l15) * 128 + g4 * 4;
  const unsigned int* A1 = hl + ((size_t)b * CN + row0 + l15) * 128 + g4 * 4;
  const unsigned int* B0 = wh + ((size_t)head * 64 + l15) * 128 + g4 * 4;
  const unsigned int* B1 = wl + ((size_t)head * 64 + l15) * 128 + g4 * 4;

  f32x4 acc[2][4];
  #pragma unroll
  for (int f = 0; f < 2; ++f)
    #pragma unroll
    for (int g = 0; g < 4; ++g) acc[f][g] = (f32x4){0.f, 0.f, 0.f, 0.f};

  for (int kw = 0; kw < 128; kw += 16) {   // 32 k per iter
    s16x8 ah[2], al[2], bhf[4], blf[4];
    #pragma unroll
    for (int f = 0; f < 2; ++f) {
      ah[f] = *(const s16x8*)(A0 + (size_t)f * 16 * 128 + kw);
      al[f] = *(const s16x8*)(A1 + (size_t)f * 16 * 128 + kw);
    }
    #pragma unroll
    for (int g = 0; g < 4; ++g) {
      bhf[g] = *(const s16x8*)(B0 + (size_t)g * 16 * 128 + kw);
      blf[g] = *(const s16x8*)(B1 + (size_t)g * 16 * 128 + kw);
    }
    #pragma unroll
    for (int f = 0; f < 2; ++f)
      #pragma unroll
      for (int g = 0; g < 4; ++g) {
        acc[f][g] = __builtin_amdgcn_mfma_f32_16x16x32_bf16(ah[f], bhf[g], acc[f][g], 0, 0, 0);
        acc[f][g] = __builtin_amdgcn_mfma_f32_16x16x32_bf16(ah[f], blf[g], acc[f][g], 0, 0, 0);
        acc[f][g] = __builtin_amdgcn_mfma_f32_16x16x32_bf16(al[f], bhf[g], acc[f][g], 0, 0, 0);
      }
  }

  // --- vsrc/vdst from acc ---
  {
    float as4[4], ad4[4];
    #pragma unroll
    for (int g = 0; g < 4; ++g) {
      as4[g] = a_src[head * CFOUT + g * 16 + l15];
      ad4[g] = a_dst[head * CFOUT + g * 16 + l15];
    }
    #pragma unroll
    for (int f = 0; f < 2; ++f) {
      float ps[4] = {0.f, 0.f, 0.f, 0.f}, pd[4] = {0.f, 0.f, 0.f, 0.f};
      #pragma unroll
      for (int g = 0; g < 4; ++g)
        #pragma unroll
        for (int q = 0; q < 4; ++q) {
          float tv = tanhf(acc[f][g][q]);
          ps[q] += tv * as4[g];
          pd[q] += tv * ad4[g];
        }
      #pragma unroll
      for (int q = 0; q < 4; ++q) {
        #pragma unroll
        for (int mm = 1; mm < 16; mm <<= 1) {
          ps[q] += __shfl_xor(ps[q], mm, 64);
          pd[q] += __shfl_xor(pd[q], mm, 64);
        }
      }
      if (l15 == 0) {
        #pragma unroll
        for (int q = 0; q < 4; ++q) {
          int row = row0 + f * 16 + g4 * 4 + q;
          vsrc[(size_t)bh * CN + row] = ps[q];
          vdst[(size_t)bh * CN + row] = pd[q];
        }
      }
    }
  }

  // --- fragment-native fB split via per-wave LDS tile ---
  {
    float* tw = tileT[wid];
    #pragma unroll
    for (int f = 0; f < 2; ++f)
      #pragma unroll
      for (int g = 0; g < 4; ++g)
        #pragma unroll
        for (int q = 0; q < 4; ++q)
          tw[(g * 16 + l15) * 33 + f * 16 + g4 * 4 + q] = acc[f][g][q];
    const int JT = (blk & 7) * 4 + wid;    // global j-tile = row0/32
    #pragma unroll
    for (int g = 0; g < 4; ++g) {
      float v[8];
      #pragma unroll
      for (int r = 0; r < 8; ++r)
        v[r] = tw[(g * 16 + l15) * 33 + g4 * 8 + r];
      unsigned int hw[4], lw[4];
      #pragma unroll
      for (int p = 0; p < 4; ++p) {
        float x0 = v[2 * p], x1 = v[2 * p + 1];
        short h0 = f2bf(x0), h1 = f2bf(x1);
        hw[p] = (unsigned int)(unsigned short)h0 | ((unsigned int)(unsigned short)h1 << 16);
        lw[p] = pkhi(x0 - bf2f(h0), x1 - bf2f(h1));
      }
      size_t base = (((size_t)bh * 32 + JT) * 4 + g) * 256 + (size_t)lane * 4;
      *(uint4*)(fBh + base) = make_uint4(hw[0], hw[1], hw[2], hw[3]);
      *(uint4*)(fBl + base) = make_uint4(lw[0], lw[1], lw[2], lw[3]);
    }
  }
}

// ---------------------------------------------------------------------------
// attn [VERIFIED round-9/10]: 512 blocks x 512 thr (8 waves), j-split.
// B fragments contiguous from fB; mask contiguous from maskT.
// ---------------------------------------------------------------------------
__global__ __launch_bounds__(512) void gat_attn_mfma(
    const unsigned int* __restrict__ maskT,
    const unsigned int* __restrict__ fBh, const unsigned int* __restrict__ fBl,
    const float* __restrict__ vsrc, const float* __restrict__ vdst,
    float* __restrict__ out) {
  __shared__ float ldsm[32 * 256 + 8 * 256];   // 40KB partial merge
  const int t = threadIdx.x, lane = t & 63, wid = t >> 6;
  const int w4 = wid & 3, grp = wid >> 2;
  const int bid = blockIdx.x;
  const int blk = (bid & 7) * 64 + (bid >> 3);   // XCD swizzle: 8 bh per XCD
  const int bh = blk >> 3, b = bh >> 3;
  const int i0 = (blk & 7) * 128 + w4 * 32;
  const int l15 = lane & 15, g4 = lane >> 4;
  const float LOG2E = 1.44269504088896340736f;

  const float* dstp = vdst + (size_t)bh * CN;

  float M = -INFINITY;
  #pragma unroll
  for (int s_ = 0; s_ < 16; ++s_) M = fmaxf(M, dstp[s_ * 64 + lane]);
  #pragma unroll
  for (int mm = 32; mm; mm >>= 1) M = fmaxf(M, __shfl_xor(M, mm, 64));

  float sA[2], sB[2];
  #pragma unroll
  for (int f = 0; f < 2; ++f) {
    float sv = vsrc[(size_t)bh * CN + i0 + f * 16 + l15];
    float c = sv + M;
    c = fmaxf(c, 0.2f * c);            // C_i = LR(src_i + M) >= row max
    float cK = c * LOG2E;
    sA[f] = sv * LOG2E - cK;
    sB[f] = 0.2f * (sv * LOG2E) - cK;
  }

  f32x4 acc[2][4], accL[2];
  #pragma unroll
  for (int f = 0; f < 2; ++f) {
    accL[f] = (f32x4){0.f, 0.f, 0.f, 0.f};
    #pragma unroll
    for (int g = 0; g < 4; ++g) acc[f][g] = (f32x4){0.f, 0.f, 0.f, 0.f};
  }

  s16x8 ones;
  {
    union { s16x8 v; unsigned int u[4]; } uo;
    unsigned int ow = (l15 == 0) ? 0x3F803F80u : 0u;
    uo.u[0] = uo.u[1] = uo.u[2] = uo.u[3] = ow;
    ones = uo.v;
  }

  const s16x8* FH = (const s16x8*)fBh + (size_t)bh * 128 * 64;
  const s16x8* FL = (const s16x8*)fBl + (size_t)bh * 128 * 64;
  const unsigned int* mT = maskT + (size_t)b * 32 * 1024;
  const int jbase = grp * 512;

  for (int j0 = jbase; j0 < jbase + 512; j0 += 32) {
    const float* dj = dstp + j0 + g4 * 8;
    float4 d0 = *(const float4*)&dj[0];
    float4 d1 = *(const float4*)&dj[4];
    float dK[8];
    dK[0] = d0.x * LOG2E; dK[1] = d0.y * LOG2E; dK[2] = d0.z * LOG2E; dK[3] = d0.w * LOG2E;
    dK[4] = d1.x * LOG2E; dK[5] = d1.y * LOG2E; dK[6] = d1.z * LOG2E; dK[7] = d1.w * LOG2E;

    const int fb0 = (j0 >> 5) * 4;
    s16x8 bhf[4], blf[4];
    #pragma unroll
    for (int g = 0; g < 4; ++g) {
      bhf[g] = FH[(size_t)(fb0 + g) * 64 + lane];
      blf[g] = FL[(size_t)(fb0 + g) * 64 + lane];
    }

    #pragma unroll
    for (int f = 0; f < 2; ++f) {
      unsigned int word = mT[(size_t)(j0 >> 5) * 1024 + i0 + f * 16 + l15];
      unsigned int byte = (word >> (g4 * 8)) & 0xFFu;
      float e[8];
      #pragma unroll
      for (int r = 0; r < 8; ++r) {
        float lr = fmaxf(sA[f] + dK[r], fmaf(0.2f, dK[r], sB[f]));
        lr = (byte & (1u << r)) ? lr : -500.f;
        e[r] = __builtin_amdgcn_exp2f(lr);
      }
      s16x8 ph;
      {
        union { s16x8 v; unsigned int u[4]; } up;
        up.u[0] = pkhi(e[0], e[1]);
        up.u[1] = pkhi(e[2], e[3]);
        up.u[2] = pkhi(e[4], e[5]);
        up.u[3] = pkhi(e[6], e[7]);
        ph = up.v;
      }
      accL[f] = __builtin_amdgcn_mfma_f32_16x16x32_bf16(ph, ones, accL[f], 0, 0, 0);
      #pragma unroll
      for (int g = 0; g < 4; ++g) {
        acc[f][g] = __builtin_amdgcn_mfma_f32_16x16x32_bf16(ph, bhf[g], acc[f][g], 0, 0, 0);
        acc[f][g] = __builtin_amdgcn_mfma_f32_16x16x32_bf16(ph, blf[g], acc[f][g], 0, 0, 0);
      }
    }
  }

  // merge group-1 partials into group-0 (lane-major LDS, conflict-free)
  const int tid = t & 255;
  if (grp == 1) {
    #pragma unroll
    for (int f = 0; f < 2; ++f) {
      #pragma unroll
      for (int g = 0; g < 4; ++g)
        #pragma unroll
        for (int q = 0; q < 4; ++q)
          ldsm[((f * 4 + g) * 4 + q) * 256 + tid] = acc[f][g][q];
      #pragma unroll
      for (int q = 0; q < 4; ++q)
        ldsm[8192 + (f * 4 + q) * 256 + tid] = accL[f][q];
    }
  }
  __syncthreads();
  if (grp == 0) {
    #pragma unroll
    for (int f = 0; f < 2; ++f) {
      #pragma unroll
      for (int g = 0; g < 4; ++g)
        #pragma unroll
        for (int q = 0; q < 4; ++q)
          acc[f][g][q] += ldsm[((f * 4 + g) * 4 + q) * 256 + tid];
      #pragma unroll
      for (int q = 0; q < 4; ++q)
        accL[f][q] += ldsm[8192 + (f * 4 + q) * 256 + tid];
    }

    #pragma unroll
    for (int f = 0; f < 2; ++f) {
      float linv[4];
      #pragma unroll
      for (int q = 0; q < 4; ++q)
        linv[q] = 1.0f / __shfl(accL[f][q], g4 << 4, 64);
      #pragma unroll
      for (int g = 0; g < 4; ++g)
        #pragma unroll
        for (int q = 0; q < 4; ++q) {
          int row = i0 + f * 16 + g4 * 4 + q;
          int col = g * 16 + l15;
          out[((size_t)bh * CN + row) * CFOUT + col] = acc[f][g][q] * linv[q];
        }
    }
  }
}

extern "C" void kernel_launch(void* const* d_in, const int* in_sizes, int n_in,
                              void* d_out, int out_size, void* d_ws, size_t ws_size,
                              hipStream_t stream) {
  const float* h     = (const float*)d_in[0];
  const int*   adj   = (const int*)d_in[1];
  const float* w     = (const float*)d_in[2];
  const float* a_src = (const float*)d_in[3];
  const float* a_dst = (const float*)d_in[4];
  float* out = (float*)d_out;

  // ws layout (26MB, no aliasing):
  //   [ 0M.. 4M) hh   [ 4M.. 8M) hl
  //   [ 8M..16M) fBh  [16M..24M) fBl
  //   [24M..24.5M) wh|wl  [24.5M..25M) vsrc|vdst  [25M..26M) maskT
  char* p = (char*)d_ws;
  unsigned int* hh  = (unsigned int*)p;
  unsigned int* hl  = (unsigned int*)(p + (size_t)(4u << 20));
  unsigned int* fBh = (unsigned int*)(p + (size_t)(8u << 20));
  unsigned int* fBl = (unsigned int*)(p + (size_t)(16u << 20));
  unsigned int* wh  = (unsigned int*)(p + (size_t)(24u << 20));
  unsigned int* wl  = (unsigned int*)(p + (size_t)(24u << 20) + (256u << 10));
  float* vs  = (float*)(p + (size_t)(24u << 20) + (512u << 10));
  float* vd  = (float*)(p + (size_t)(24u << 20) + (768u << 10));
  unsigned int* maskT = (unsigned int*)(p + (size_t)(25u << 20));

  hipLaunchKernelGGL(prep, dim3(1032 + 2048), dim3(256), 0, stream,
                     h, w, adj, hh, hl, wh, wl, maskT);
  hipLaunchKernelGGL(liteF, dim3(512), dim3(256), 0, stream,
                     hh, hl, wh, wl, a_src, a_dst, fBh, fBl, vs, vd);
  hipLaunchKernelGGL(gat_attn_mfma, dim3(512), dim3(512), 0, stream,
                     maskT, fBh, fBl, vs, vd, out);
}

// Round 12
// 65.482 us; speedup vs baseline: 3.5094x; 1.2216x over previous
//
#include <hip/hip_runtime.h>
#include <math.h>

constexpr int CBS   = 8;
constexpr int CN    = 1024;
constexpr int CFIN  = 256;
constexpr int CNH   = 8;
constexpr int CFOUT = 64;

using f32x4 = __attribute__((ext_vector_type(4))) float;
using s16x8 = __attribute__((ext_vector_type(8))) short;

__device__ __forceinline__ short f2bf(float x) {
  __bf16 b = (__bf16)x;
  return __builtin_bit_cast(short, b);
}
__device__ __forceinline__ float bf2f(short s) {
  __bf16 b = __builtin_bit_cast(__bf16, s);
  return (float)b;
}
__device__ __forceinline__ unsigned int pkhi(float a, float b) {
  return (unsigned int)(unsigned short)f2bf(a) |
         ((unsigned int)(unsigned short)f2bf(b) << 16);
}

// ---------------------------------------------------------------------------
// prep: conv_h (blocks 0..1023) -> hh/hl in A-FRAGMENT-NATIVE layout
//         frag(b, RT, kwI): lane l = g4*16+l15 holds row RT*16+l15,
//         u32 words gi*4..gi*4+3 where gi = kwI*4+g4. dst uint4 index =
//         ((b*64+RT)*8+kwI)*64 + lane. Same data as round-11, new address.
//       conv_w (blocks 1024..1031) -> wh/wl in B-FRAGMENT-NATIVE layout
//         frag(head, g, kwI): lane holds o-row g*16+l15, words kwI*16+g4*4..+3
//         dst uint4 index = ((head*4+g)*8+kwI)*64 + lane.
//       packT [verified round-11 fat-wave] (blocks 1032..3079).
// ---------------------------------------------------------------------------
__global__ __launch_bounds__(256) void prep(
    const float* __restrict__ h, const float* __restrict__ w,
    const int* __restrict__ adj,
    unsigned int* __restrict__ hh, unsigned int* __restrict__ hl,
    unsigned int* __restrict__ wh, unsigned int* __restrict__ wl,
    unsigned int* __restrict__ maskT) {
  const int blk = blockIdx.x, t = threadIdx.x;
  if (blk < 1024) {
    size_t i = (size_t)blk * 256 + t;          // uint4 index in [0, 262144)
    const int gi = (int)(i & 31);
    const int n  = (int)((i >> 5) & 1023);
    const int b  = (int)(i >> 15);
    const float4* src = (const float4*)(h + i * 8);
    float4 a = src[0], bb = src[1];
    float v[8] = {a.x, a.y, a.z, a.w, bb.x, bb.y, bb.z, bb.w};
    unsigned int hw[4], lw[4];
    #pragma unroll
    for (int p = 0; p < 4; ++p) {
      float x0 = v[2 * p], x1 = v[2 * p + 1];
      short h0 = f2bf(x0), h1 = f2bf(x1);
      hw[p] = (unsigned int)(unsigned short)h0 | ((unsigned int)(unsigned short)h1 << 16);
      lw[p] = pkhi(x0 - bf2f(h0), x1 - bf2f(h1));
    }
    const int RT = n >> 4, l15v = n & 15, kwI = gi >> 2, g4v = gi & 3;
    size_t dst = (((size_t)b * 64 + RT) * 8 + kwI) * 64 + (g4v * 16 + l15v);
    ((uint4*)hh)[dst] = make_uint4(hw[0], hw[1], hw[2], hw[3]);
    ((uint4*)hl)[dst] = make_uint4(lw[0], lw[1], lw[2], lw[3]);
  } else if (blk < 1032) {
    const int head = blk - 1024;
    const int o = t & 63, kc = (t >> 6) * 64;
    const int g = o >> 4, l15v = o & 15;
    const float* wg = w + (size_t)head * CFIN * CFOUT;
    #pragma unroll
    for (int j = 0; j < 8; ++j) {
      const int gi = (kc >> 3) + j;            // 0..31
      const int kwI = gi >> 2, g4v = gi & 3;
      unsigned int hw[4], lw[4];
      #pragma unroll
      for (int p = 0; p < 4; ++p) {
        int k = gi * 8 + 2 * p;
        float x0 = wg[(size_t)k * 64 + o], x1 = wg[(size_t)(k + 1) * 64 + o];
        short h0 = f2bf(x0), h1 = f2bf(x1);
        hw[p] = (unsigned int)(unsigned short)h0 | ((unsigned int)(unsigned short)h1 << 16);
        lw[p] = pkhi(x0 - bf2f(h0), x1 - bf2f(h1));
      }
      size_t dst = (((size_t)head * 4 + g) * 8 + kwI) * 64 + (g4v * 16 + l15v);
      ((uint4*)wh)[dst] = make_uint4(hw[0], hw[1], hw[2], hw[3]);
      ((uint4*)wl)[dst] = make_uint4(lw[0], lw[1], lw[2], lw[3]);
    }
  } else {
    const int lane = t & 63, wv = t >> 6;
    const long long bi = (long long)(blk - 1032) * 4 + wv;   // b*1024 + i
    const int b = (int)(bi >> 10), i = (int)(bi & 1023);
    const int* ap = adj + bi * 1024 + lane;
    int a[16];
    #pragma unroll
    for (int jw = 0; jw < 16; ++jw) a[jw] = ap[jw * 64];     // 16 loads in flight
    #pragma unroll
    for (int jw = 0; jw < 16; ++jw) {
      unsigned long long m = __ballot(a[jw] > 0);
      if (lane == 0) {
        maskT[((size_t)b * 32 + jw * 2 + 0) * 1024 + i] = (unsigned int)m;
        maskT[((size_t)b * 32 + jw * 2 + 1) * 1024 + i] = (unsigned int)(m >> 32);
      }
    }
  }
}

// ---------------------------------------------------------------------------
// liteF [round-11 verified core; A/B loads now CONTIGUOUS fragment-native]:
// 512 blocks. hp = h@w via hi/lo 3-MFMA split; epilogue writes vsrc/vdst and
// fragment-native fB hi/lo (per-wave LDS tile, no syncthreads).
// ---------------------------------------------------------------------------
__global__ __launch_bounds__(256) void liteF(
    const unsigned int* __restrict__ hh, const unsigned int* __restrict__ hl,
    const unsigned int* __restrict__ wh, const unsigned int* __restrict__ wl,
    const float* __restrict__ a_src, const float* __restrict__ a_dst,
    unsigned int* __restrict__ fBh, unsigned int* __restrict__ fBl,
    float* __restrict__ vsrc, float* __restrict__ vdst) {
  __shared__ float tileT[4][64 * 33];   // per-wave [o][n_local], pad 33
  const int bid = blockIdx.x, t = threadIdx.x;
  const int lane = t & 63, wid = t >> 6;
  const int blk = (bid & 7) * 64 + (bid >> 3);   // XCD swizzle: one b per XCD
  const int bh = blk >> 3, head = bh & 7, b = bh >> 3;
  const int row0 = (blk & 7) * 128 + wid * 32;
  const int l15 = lane & 15, g4 = lane >> 4;

  const uint4* A0 = (const uint4*)hh + (((size_t)b * 64 + (row0 >> 4)) * 8) * 64 + lane;
  const uint4* A1 = (const uint4*)hl + (((size_t)b * 64 + (row0 >> 4)) * 8) * 64 + lane;
  const uint4* B0 = (const uint4*)wh + ((size_t)head * 4 * 8) * 64 + lane;
  const uint4* B1 = (const uint4*)wl + ((size_t)head * 4 * 8) * 64 + lane;

  f32x4 acc[2][4];
  #pragma unroll
  for (int f = 0; f < 2; ++f)
    #pragma unroll
    for (int g = 0; g < 4; ++g) acc[f][g] = (f32x4){0.f, 0.f, 0.f, 0.f};

  for (int kwI = 0; kwI < 8; ++kwI) {   // 32 k per iter
    s16x8 ah[2], al[2], bhf[4], blf[4];
    #pragma unroll
    for (int f = 0; f < 2; ++f) {
      ah[f] = *(const s16x8*)(A0 + (size_t)(f * 8 + kwI) * 64);
      al[f] = *(const s16x8*)(A1 + (size_t)(f * 8 + kwI) * 64);
    }
    #pragma unroll
    for (int g = 0; g < 4; ++g) {
      bhf[g] = *(const s16x8*)(B0 + (size_t)(g * 8 + kwI) * 64);
      blf[g] = *(const s16x8*)(B1 + (size_t)(g * 8 + kwI) * 64);
    }
    #pragma unroll
    for (int f = 0; f < 2; ++f)
      #pragma unroll
      for (int g = 0; g < 4; ++g) {
        acc[f][g] = __builtin_amdgcn_mfma_f32_16x16x32_bf16(ah[f], bhf[g], acc[f][g], 0, 0, 0);
        acc[f][g] = __builtin_amdgcn_mfma_f32_16x16x32_bf16(ah[f], blf[g], acc[f][g], 0, 0, 0);
        acc[f][g] = __builtin_amdgcn_mfma_f32_16x16x32_bf16(al[f], bhf[g], acc[f][g], 0, 0, 0);
      }
  }

  // --- vsrc/vdst from acc [verified round-10/11] ---
  {
    float as4[4], ad4[4];
    #pragma unroll
    for (int g = 0; g < 4; ++g) {
      as4[g] = a_src[head * CFOUT + g * 16 + l15];
      ad4[g] = a_dst[head * CFOUT + g * 16 + l15];
    }
    #pragma unroll
    for (int f = 0; f < 2; ++f) {
      float ps[4] = {0.f, 0.f, 0.f, 0.f}, pd[4] = {0.f, 0.f, 0.f, 0.f};
      #pragma unroll
      for (int g = 0; g < 4; ++g)
        #pragma unroll
        for (int q = 0; q < 4; ++q) {
          float tv = tanhf(acc[f][g][q]);
          ps[q] += tv * as4[g];
          pd[q] += tv * ad4[g];
        }
      #pragma unroll
      for (int q = 0; q < 4; ++q) {
        #pragma unroll
        for (int mm = 1; mm < 16; mm <<= 1) {
          ps[q] += __shfl_xor(ps[q], mm, 64);
          pd[q] += __shfl_xor(pd[q], mm, 64);
        }
      }
      if (l15 == 0) {
        #pragma unroll
        for (int q = 0; q < 4; ++q) {
          int row = row0 + f * 16 + g4 * 4 + q;
          vsrc[(size_t)bh * CN + row] = ps[q];
          vdst[(size_t)bh * CN + row] = pd[q];
        }
      }
    }
  }

  // --- fragment-native fB split via per-wave LDS tile [verified round-10/11] ---
  {
    float* tw = tileT[wid];
    #pragma unroll
    for (int f = 0; f < 2; ++f)
      #pragma unroll
      for (int g = 0; g < 4; ++g)
        #pragma unroll
        for (int q = 0; q < 4; ++q)
          tw[(g * 16 + l15) * 33 + f * 16 + g4 * 4 + q] = acc[f][g][q];
    const int JT = (blk & 7) * 4 + wid;    // global j-tile = row0/32
    #pragma unroll
    for (int g = 0; g < 4; ++g) {
      float v[8];
      #pragma unroll
      for (int r = 0; r < 8; ++r)
        v[r] = tw[(g * 16 + l15) * 33 + g4 * 8 + r];
      unsigned int hw[4], lw[4];
      #pragma unroll
      for (int p = 0; p < 4; ++p) {
        float x0 = v[2 * p], x1 = v[2 * p + 1];
        short h0 = f2bf(x0), h1 = f2bf(x1);
        hw[p] = (unsigned int)(unsigned short)h0 | ((unsigned int)(unsigned short)h1 << 16);
        lw[p] = pkhi(x0 - bf2f(h0), x1 - bf2f(h1));
      }
      size_t base = (((size_t)bh * 32 + JT) * 4 + g) * 256 + (size_t)lane * 4;
      *(uint4*)(fBh + base) = make_uint4(hw[0], hw[1], hw[2], hw[3]);
      *(uint4*)(fBl + base) = make_uint4(lw[0], lw[1], lw[2], lw[3]);
    }
  }
}

// ---------------------------------------------------------------------------
// attn [VERIFIED round-9/10/11, verbatim]: 512 blocks x 512 thr, j-split.
// ---------------------------------------------------------------------------
__global__ __launch_bounds__(512) void gat_attn_mfma(
    const unsigned int* __restrict__ maskT,
    const unsigned int* __restrict__ fBh, const unsigned int* __restrict__ fBl,
    const float* __restrict__ vsrc, const float* __restrict__ vdst,
    float* __restrict__ out) {
  __shared__ float ldsm[32 * 256 + 8 * 256];   // 40KB partial merge
  const int t = threadIdx.x, lane = t & 63, wid = t >> 6;
  const int w4 = wid & 3, grp = wid >> 2;
  const int bid = blockIdx.x;
  const int blk = (bid & 7) * 64 + (bid >> 3);   // XCD swizzle: 8 bh per XCD
  const int bh = blk >> 3, b = bh >> 3;
  const int i0 = (blk & 7) * 128 + w4 * 32;
  const int l15 = lane & 15, g4 = lane >> 4;
  const float LOG2E = 1.44269504088896340736f;

  const float* dstp = vdst + (size_t)bh * CN;

  float M = -INFINITY;
  #pragma unroll
  for (int s_ = 0; s_ < 16; ++s_) M = fmaxf(M, dstp[s_ * 64 + lane]);
  #pragma unroll
  for (int mm = 32; mm; mm >>= 1) M = fmaxf(M, __shfl_xor(M, mm, 64));

  float sA[2], sB[2];
  #pragma unroll
  for (int f = 0; f < 2; ++f) {
    float sv = vsrc[(size_t)bh * CN + i0 + f * 16 + l15];
    float c = sv + M;
    c = fmaxf(c, 0.2f * c);            // C_i = LR(src_i + M) >= row max
    float cK = c * LOG2E;
    sA[f] = sv * LOG2E - cK;
    sB[f] = 0.2f * (sv * LOG2E) - cK;
  }

  f32x4 acc[2][4], accL[2];
  #pragma unroll
  for (int f = 0; f < 2; ++f) {
    accL[f] = (f32x4){0.f, 0.f, 0.f, 0.f};
    #pragma unroll
    for (int g = 0; g < 4; ++g) acc[f][g] = (f32x4){0.f, 0.f, 0.f, 0.f};
  }

  s16x8 ones;
  {
    union { s16x8 v; unsigned int u[4]; } uo;
    unsigned int ow = (l15 == 0) ? 0x3F803F80u : 0u;
    uo.u[0] = uo.u[1] = uo.u[2] = uo.u[3] = ow;
    ones = uo.v;
  }

  const s16x8* FH = (const s16x8*)fBh + (size_t)bh * 128 * 64;
  const s16x8* FL = (const s16x8*)fBl + (size_t)bh * 128 * 64;
  const unsigned int* mT = maskT + (size_t)b * 32 * 1024;
  const int jbase = grp * 512;

  for (int j0 = jbase; j0 < jbase + 512; j0 += 32) {
    const float* dj = dstp + j0 + g4 * 8;
    float4 d0 = *(const float4*)&dj[0];
    float4 d1 = *(const float4*)&dj[4];
    float dK[8];
    dK[0] = d0.x * LOG2E; dK[1] = d0.y * LOG2E; dK[2] = d0.z * LOG2E; dK[3] = d0.w * LOG2E;
    dK[4] = d1.x * LOG2E; dK[5] = d1.y * LOG2E; dK[6] = d1.z * LOG2E; dK[7] = d1.w * LOG2E;

    const int fb0 = (j0 >> 5) * 4;
    s16x8 bhf[4], blf[4];
    #pragma unroll
    for (int g = 0; g < 4; ++g) {
      bhf[g] = FH[(size_t)(fb0 + g) * 64 + lane];
      blf[g] = FL[(size_t)(fb0 + g) * 64 + lane];
    }

    #pragma unroll
    for (int f = 0; f < 2; ++f) {
      unsigned int word = mT[(size_t)(j0 >> 5) * 1024 + i0 + f * 16 + l15];
      unsigned int byte = (word >> (g4 * 8)) & 0xFFu;
      float e[8];
      #pragma unroll
      for (int r = 0; r < 8; ++r) {
        float lr = fmaxf(sA[f] + dK[r], fmaf(0.2f, dK[r], sB[f]));
        lr = (byte & (1u << r)) ? lr : -500.f;
        e[r] = __builtin_amdgcn_exp2f(lr);
      }
      s16x8 ph;
      {
        union { s16x8 v; unsigned int u[4]; } up;
        up.u[0] = pkhi(e[0], e[1]);
        up.u[1] = pkhi(e[2], e[3]);
        up.u[2] = pkhi(e[4], e[5]);
        up.u[3] = pkhi(e[6], e[7]);
        ph = up.v;
      }
      accL[f] = __builtin_amdgcn_mfma_f32_16x16x32_bf16(ph, ones, accL[f], 0, 0, 0);
      #pragma unroll
      for (int g = 0; g < 4; ++g) {
        acc[f][g] = __builtin_amdgcn_mfma_f32_16x16x32_bf16(ph, bhf[g], acc[f][g], 0, 0, 0);
        acc[f][g] = __builtin_amdgcn_mfma_f32_16x16x32_bf16(ph, blf[g], acc[f][g], 0, 0, 0);
      }
    }
  }

  // merge group-1 partials into group-0 (lane-major LDS, conflict-free)
  const int tid = t & 255;
  if (grp == 1) {
    #pragma unroll
    for (int f = 0; f < 2; ++f) {
      #pragma unroll
      for (int g = 0; g < 4; ++g)
        #pragma unroll
        for (int q = 0; q < 4; ++q)
          ldsm[((f * 4 + g) * 4 + q) * 256 + tid] = acc[f][g][q];
      #pragma unroll
      for (int q = 0; q < 4; ++q)
        ldsm[8192 + (f * 4 + q) * 256 + tid] = accL[f][q];
    }
  }
  __syncthreads();
  if (grp == 0) {
    #pragma unroll
    for (int f = 0; f < 2; ++f) {
      #pragma unroll
      for (int g = 0; g < 4; ++g)
        #pragma unroll
        for (int q = 0; q < 4; ++q)
          acc[f][g][q] += ldsm[((f * 4 + g) * 4 + q) * 256 + tid];
      #pragma unroll
      for (int q = 0; q < 4; ++q)
        accL[f][q] += ldsm[8192 + (f * 4 + q) * 256 + tid];
    }

    #pragma unroll
    for (int f = 0; f < 2; ++f) {
      float linv[4];
      #pragma unroll
      for (int q = 0; q < 4; ++q)
        linv[q] = 1.0f / __shfl(accL[f][q], g4 << 4, 64);
      #pragma unroll
      for (int g = 0; g < 4; ++g)
        #pragma unroll
        for (int q = 0; q < 4; ++q) {
          int row = i0 + f * 16 + g4 * 4 + q;
          int col = g * 16 + l15;
          out[((size_t)bh * CN + row) * CFOUT + col] = acc[f][g][q] * linv[q];
        }
    }
  }
}

extern "C" void kernel_launch(void* const* d_in, const int* in_sizes, int n_in,
                              void* d_out, int out_size, void* d_ws, size_t ws_size,
                              hipStream_t stream) {
  const float* h     = (const float*)d_in[0];
  const int*   adj   = (const int*)d_in[1];
  const float* w     = (const float*)d_in[2];
  const float* a_src = (const float*)d_in[3];
  const float* a_dst = (const float*)d_in[4];
  float* out = (float*)d_out;

  // ws layout (26MB, no aliasing):
  //   [ 0M.. 4M) hh   [ 4M.. 8M) hl
  //   [ 8M..16M) fBh  [16M..24M) fBl
  //   [24M..24.5M) wh|wl  [24.5M..25M) vsrc|vdst  [25M..26M) maskT
  char* p = (char*)d_ws;
  unsigned int* hh  = (unsigned int*)p;
  unsigned int* hl  = (unsigned int*)(p + (size_t)(4u << 20));
  unsigned int* fBh = (unsigned int*)(p + (size_t)(8u << 20));
  unsigned int* fBl = (unsigned int*)(p + (size_t)(16u << 20));
  unsigned int* wh  = (unsigned int*)(p + (size_t)(24u << 20));
  unsigned int* wl  = (unsigned int*)(p + (size_t)(24u << 20) + (256u << 10));
  float* vs  = (float*)(p + (size_t)(24u << 20) + (512u << 10));
  float* vd  = (float*)(p + (size_t)(24u << 20) + (768u << 10));
  unsigned int* maskT = (unsigned int*)(p + (size_t)(25u << 20));

  hipLaunchKernelGGL(prep, dim3(1032 + 2048), dim3(256), 0, stream,
                     h, w, adj, hh, hl, wh, wl, maskT);
  hipLaunchKernelGGL(liteF, dim3(512), dim3(256), 0, stream,
                     hh, hl, wh, wl, a_src, a_dst, fBh, fBl, vs, vd);
  hipLaunchKernelGGL(gat_attn_mfma, dim3(512), dim3(512), 0, stream,
                     maskT, fBh, fBl, vs, vd, out);
}